// Round 1
// baseline (1846.178 us; speedup 1.0000x reference)
//
#include <hip/hip_runtime.h>
#include <hip/hip_bf16.h>
#include <math.h>

// Problem constants
#define B_ 256
#define S_ 24
#define N_ 207
#define U_ 64
#define A_ 256
#define H_ (N_*U_)          // 13248
#define BS_ (B_*S_)         // 6144
#define NF_ 129             // 1 + 2U
#define CATW_ (B_*NF_)      // 33024  (CAT row width, (N, B, F) layout)
#define BN_ROWS_ (N_*B_)    // 52992  (rows of Mbuf viewed as (N*B, 129), row = n*256+b)

// ---------------------------------------------------------------------------
// Generic fp32 tile GEMM: C[M,N] = A[M,K](row-major,lda) @ B[K,N](row-major,ldb)
// BM=BN=64, BK=16, 256 threads, 4x4 per thread. Optional K-chunking over
// blockIdx.z (kchunk>0) for split-K with EPI=1 (atomicAdd).
// EPI: 0 = store, 1 = atomicAdd, 2 = sigmoid(acc + ep0[col]),
//      3 = GRU epilogue: cg=tanh(acc+ep0[col]); u=ep1[row*128+64+col];
//          h=ep2[b*H+n*U+col]; out[b*H+n*U+col] = u*h+(1-u)*cg  (row=n*256+b)
// ---------------------------------------------------------------------------
template<int BM, int BN, int BK, int TM, int TN, int EPI>
__global__ __launch_bounds__(256)
void gemm_f32(const float* __restrict__ A, int lda,
              const float* __restrict__ Bm, int ldb,
              float* __restrict__ C, int ldc,
              int M, int N, int K, int kchunk,
              const float* __restrict__ ep0,
              const float* __restrict__ ep1,
              const float* __restrict__ ep2)
{
    __shared__ float As[BK][BM + 4];   // +4 keeps 16B alignment, avoids conflicts
    __shared__ float Bs[BK][BN + 4];

    const int tid = threadIdx.x;
    const int tx = tid % (BN / TN);    // 0..15 (col group)
    const int ty = tid / (BN / TN);    // 0..15 (row group)
    const int m0 = blockIdx.y * BM;
    const int n0 = blockIdx.x * BN;

    int kb = 0, ke = K;
    if (kchunk > 0) { kb = blockIdx.z * kchunk; ke = min(K, kb + kchunk); }

    float acc[TM][TN];
    #pragma unroll
    for (int i = 0; i < TM; ++i)
        #pragma unroll
        for (int j = 0; j < TN; ++j) acc[i][j] = 0.f;

    for (int k0 = kb; k0 < ke; k0 += BK) {
        // A tile: BM x BK  -> As[k][m]
        #pragma unroll
        for (int i = tid; i < BM * BK; i += 256) {
            int r = i / BK, c = i % BK;
            int gm = m0 + r, gk = k0 + c;
            As[c][r] = (gm < M && gk < ke) ? A[(size_t)gm * lda + gk] : 0.f;
        }
        // B tile: BK x BN -> Bs[k][n]
        #pragma unroll
        for (int i = tid; i < BK * BN; i += 256) {
            int r = i / BN, c = i % BN;
            int gk = k0 + r, gn = n0 + c;
            Bs[r][c] = (gk < ke && gn < N) ? Bm[(size_t)gk * ldb + gn] : 0.f;
        }
        __syncthreads();
        #pragma unroll
        for (int kk = 0; kk < BK; ++kk) {
            float a[TM], b[TN];
            #pragma unroll
            for (int i = 0; i < TM; ++i) a[i] = As[kk][ty * TM + i];
            #pragma unroll
            for (int j = 0; j < TN; ++j) b[j] = Bs[kk][tx * TN + j];
            #pragma unroll
            for (int i = 0; i < TM; ++i)
                #pragma unroll
                for (int j = 0; j < TN; ++j)
                    acc[i][j] += a[i] * b[j];
        }
        __syncthreads();
    }

    #pragma unroll
    for (int i = 0; i < TM; ++i) {
        int row = m0 + ty * TM + i;
        if (row >= M) continue;
        #pragma unroll
        for (int j = 0; j < TN; ++j) {
            int col = n0 + tx * TN + j;
            if (col >= N) continue;
            if (EPI == 0) {
                C[(size_t)row * ldc + col] = acc[i][j];
            } else if (EPI == 1) {
                atomicAdd(&C[(size_t)row * ldc + col], acc[i][j]);
            } else if (EPI == 2) {
                float sv = acc[i][j] + ep0[col];
                C[(size_t)row * ldc + col] = 1.f / (1.f + expf(-sv));
            } else { // EPI == 3
                int nn = row >> 8, bb = row & 255;
                float cg = tanhf(acc[i][j] + ep0[col]);
                float ug = ep1[(size_t)row * 128 + 64 + col];
                float hh = ep2[(size_t)bb * H_ + nn * U_ + col];
                C[(size_t)bb * H_ + nn * U_ + col] = ug * hh + (1.f - ug) * cg;
            }
        }
    }
}

// T1[b*256+a] = attn_b[a]   (then GEMM atomically adds hid@Wh)
__global__ __launch_bounds__(256)
void t1init_kernel(const float* __restrict__ ab, float* __restrict__ T1) {
    int i = blockIdx.x * 256 + threadIdx.x;   // 65536 total
    T1[i] = ab[i & 255];
}

// scores[q] = sum_a tanh(P[q,a] + T1[b,a]) * v[a],  q = s*256+b
__global__ __launch_bounds__(256)
void scores_kernel(const float* __restrict__ P, const float* __restrict__ T1,
                   const float* __restrict__ v, float* __restrict__ SC) {
    int wave = threadIdx.x >> 6, lane = threadIdx.x & 63;
    int q = blockIdx.x * 4 + wave;
    if (q >= BS_) return;
    int b = q & 255;
    float s = 0.f;
    #pragma unroll
    for (int a = lane; a < A_; a += 64) {
        float e = tanhf(P[(size_t)q * A_ + a] + T1[b * A_ + a]);
        s += e * v[a];
    }
    #pragma unroll
    for (int off = 32; off; off >>= 1) s += __shfl_down(s, off, 64);
    if (lane == 0) SC[q] = s;
}

// softmax over s (24) for each b; SC/AW layout [s][b]
__global__ __launch_bounds__(256)
void softmax_kernel(const float* __restrict__ SC, float* __restrict__ AW) {
    int b = threadIdx.x;
    float mx = -1e30f;
    for (int s = 0; s < S_; ++s) mx = fmaxf(mx, SC[s * B_ + b]);
    float sum = 0.f;
    for (int s = 0; s < S_; ++s) sum += expf(SC[s * B_ + b] - mx);
    float inv = 1.f / sum;
    for (int s = 0; s < S_; ++s) AW[s * B_ + b] = expf(SC[s * B_ + b] - mx) * inv;
}

// weighted[b,h] = sum_s AW[s,b] * enc[s,b,h]   (float4 over h)
__global__ __launch_bounds__(256)
void weighted_kernel(const float4* __restrict__ E4, const float* __restrict__ AW,
                     float4* __restrict__ WT4) {
    int g = blockIdx.x * 256 + threadIdx.x;            // B_*H_/4 = 847872
    if (g >= B_ * (H_ / 4)) return;
    int b = g / (H_ / 4), c = g % (H_ / 4);
    float4 acc = make_float4(0.f, 0.f, 0.f, 0.f);
    #pragma unroll
    for (int s = 0; s < S_; ++s) {
        float w = AW[s * B_ + b];
        float4 ev = E4[(size_t)(s * B_ + b) * (H_ / 4) + c];
        acc.x += w * ev.x; acc.y += w * ev.y;
        acc.z += w * ev.z; acc.w += w * ev.w;
    }
    WT4[(size_t)b * (H_ / 4) + c] = acc;
}

// CAT (N, B, 129): f=0 -> inputs, 1..64 -> weighted, 65..128 -> hid
__global__ __launch_bounds__(256)
void cat1_kernel(const float* __restrict__ inp, const float* __restrict__ WT,
                 const float* __restrict__ hid, float* __restrict__ CAT) {
    int idx = blockIdx.x * 256 + threadIdx.x;          // N_*B_*129 = 6835968
    if (idx >= N_ * CATW_) return;
    int m = idx / CATW_;
    int rem = idx % CATW_;
    int b = rem / NF_, f = rem % NF_;
    float val;
    if (f == 0)       val = inp[b * N_ + m];
    else if (f <= 64) val = WT[(size_t)b * H_ + m * U_ + (f - 1)];
    else              val = hid[(size_t)b * H_ + m * U_ + (f - 65)];
    CAT[(size_t)idx] = val;
}

// overwrite CAT cols 65..128 with r*h  (r = RU[:, 0:64])
__global__ __launch_bounds__(256)
void cat2_kernel(const float* __restrict__ RU, const float* __restrict__ hid,
                 float* __restrict__ CAT) {
    int idx = blockIdx.x * 256 + threadIdx.x;          // N_*B_*64 = 3391488
    if (idx >= N_ * B_ * U_) return;
    int m = idx / (B_ * U_);
    int rem = idx % (B_ * U_);
    int b = rem / U_, u = rem % U_;
    float r = RU[(size_t)(m * B_ + b) * 128 + u];
    float h = hid[(size_t)b * H_ + m * U_ + u];
    CAT[(size_t)m * CATW_ + b * NF_ + 65 + u] = r * h;
}

// output[b,n] = proj_b + sum_f proj_in[f]*proj_W[f]
// proj_in = [new_h(64) | weighted(64) | inputs(1)]; one wave per (b,n)
__global__ __launch_bounds__(256)
void proj_kernel(const float* __restrict__ newh, const float* __restrict__ WT,
                 const float* __restrict__ inp, const float* __restrict__ pW,
                 const float* __restrict__ pb, float* __restrict__ out0) {
    int wave = threadIdx.x >> 6, lane = threadIdx.x & 63;
    int idx = blockIdx.x * 4 + wave;                   // 52992 (b,n) pairs
    if (idx >= B_ * N_) return;
    int b = idx / N_, n = idx % N_;
    float t = newh[(size_t)b * H_ + n * U_ + lane] * pW[lane]
            + WT  [(size_t)b * H_ + n * U_ + lane] * pW[64 + lane];
    if (lane == 0) t += inp[b * N_ + n] * pW[128] + pb[0];
    #pragma unroll
    for (int off = 32; off; off >>= 1) t += __shfl_down(t, off, 64);
    if (lane == 0) out0[b * N_ + n] = t;
}

extern "C" void kernel_launch(void* const* d_in, const int* in_sizes, int n_in,
                              void* d_out, int out_size, void* d_ws, size_t ws_size,
                              hipStream_t stream) {
    const float* inp    = (const float*)d_in[0];   // (B, N)
    const float* enc    = (const float*)d_in[1];   // (S, B, H)
    const float* hid    = (const float*)d_in[2];   // (1, B, H) -> (B, H)
    const float* adj    = (const float*)d_in[3];   // (N, N)
    const float* attn_W = (const float*)d_in[4];   // (2H, A)
    const float* attn_b = (const float*)d_in[5];   // (A,)
    const float* attn_v = (const float*)d_in[6];   // (A,)
    const float* W_ru   = (const float*)d_in[7];   // (129, 128)
    const float* b_ru   = (const float*)d_in[8];   // (128,)
    const float* W_c    = (const float*)d_in[9];   // (129, 64)
    const float* b_c    = (const float*)d_in[10];  // (64,)
    const float* proj_W = (const float*)d_in[11];  // (129,)
    const float* proj_b = (const float*)d_in[12];  // (1,)

    float* out0 = (float*)d_out;                   // (B, N)
    float* out2 = out0 + (size_t)B_ * N_;          // new_h (B, H)

    // Workspace layout (floats). Total 25,497,088 floats = ~97.3 MB.
    float* ws  = (float*)d_ws;
    float* T1  = ws;                  // 65536      hid@Wh + attn_b
    float* P   = T1  + 65536;         // 1572864    enc@We raw (q = s*256+b major)
    float* SC  = P   + 1572864;       // 6144       scores [s][b]
    float* AW  = SC  + 6144;          // 6144       softmax weights [s][b]
    float* WT  = AW  + 6144;          // 3391488    weighted (B, H)
    float* CAT = WT  + 3391488;       // 6835968    cat (N, B, 129)
    float* MB  = CAT + 6835968;       // 6835968    m / mc  (N, B*129)
    float* RU  = MB  + 6835968;       // 6782976    sigmoid gates (N*B, 128)

    // zero split-K accumulators (every call: graph replays)
    hipMemsetAsync(P, 0, (size_t)1572864 * sizeof(float), stream);
    t1init_kernel<<<256, 256, 0, stream>>>(attn_b, T1);

    // K1: T1 += hid @ Wh   (M=256,N=256,K=13248, split-K 52)
    gemm_f32<64,64,16,4,4,1><<<dim3(4,4,52), 256, 0, stream>>>(
        hid, H_, attn_W, A_, T1, A_, B_, A_, H_, 256, nullptr, nullptr, nullptr);

    // K2: P += enc @ We    (M=6144,N=256,K=13248, split-K 2 for 768 blocks)
    gemm_f32<64,64,16,4,4,1><<<dim3(4,96,2), 256, 0, stream>>>(
        enc, H_, attn_W + (size_t)H_ * A_, A_, P, A_, BS_, A_, H_, 6624,
        nullptr, nullptr, nullptr);

    // K3: scores[q] = sum_a tanh(P+T1)*v
    scores_kernel<<<BS_/4, 256, 0, stream>>>(P, T1, attn_v, SC);

    // K4: softmax over s per b
    softmax_kernel<<<1, 256, 0, stream>>>(SC, AW);

    // K5: weighted = sum_s a[s,b] * enc[s,b,:]
    weighted_kernel<<<(B_*(H_/4))/256, 256, 0, stream>>>(
        (const float4*)enc, AW, (float4*)WT);

    // K6: build CAT (N,B,129) = [inputs | weighted | hid]
    cat1_kernel<<<(N_*CATW_)/256, 256, 0, stream>>>(inp, WT, hid, CAT);

    // K7: MB = adj @ CAT   (M=207, N=33024, K=207)
    gemm_f32<64,64,16,4,4,0><<<dim3(CATW_/64, 4, 1), 256, 0, stream>>>(
        adj, N_, CAT, CATW_, MB, CATW_, N_, CATW_, N_, 0, nullptr, nullptr, nullptr);

    // K8: RU = sigmoid(MB_rows @ W_ru + b_ru)  (M=52992, N=128, K=129)
    gemm_f32<64,64,16,4,4,2><<<dim3(2, BN_ROWS_/64, 1), 256, 0, stream>>>(
        MB, NF_, W_ru, 128, RU, 128, BN_ROWS_, 128, NF_, 0, b_ru, nullptr, nullptr);

    // K9: CAT cols 65..128 = r*h
    cat2_kernel<<<(N_*B_*U_)/256, 256, 0, stream>>>(RU, hid, CAT);

    // K10: MB = adj @ CAT  (mc)
    gemm_f32<64,64,16,4,4,0><<<dim3(CATW_/64, 4, 1), 256, 0, stream>>>(
        adj, N_, CAT, CATW_, MB, CATW_, N_, CATW_, N_, 0, nullptr, nullptr, nullptr);

    // K11: c = tanh(MB @ W_c + b_c); new_h = u*h + (1-u)*c -> out2
    gemm_f32<64,64,16,4,4,3><<<dim3(1, BN_ROWS_/64, 1), 256, 0, stream>>>(
        MB, NF_, W_c, U_, out2, U_, BN_ROWS_, U_, NF_, 0, b_c, RU, hid);

    // K12: output projection
    proj_kernel<<<(B_*N_)/4, 256, 0, stream>>>(out2, WT, inp, proj_W, proj_b, out0);
}

// Round 2
// 579.680 us; speedup vs baseline: 3.1848x; 3.1848x over previous
//
#include <hip/hip_runtime.h>
#include <hip/hip_bf16.h>
#include <math.h>

// Problem constants
#define B_ 256
#define S_ 24
#define N_ 207
#define U_ 64
#define A_ 256
#define H_ (N_*U_)          // 13248
#define H2_ (2*H_)          // 26496
#define BS_ (B_*S_)         // 6144
#define NF_ 129             // 1 + 2U
#define CATW_ (B_*NF_)      // 33024
#define BN_ROWS_ (N_*B_)    // 52992

typedef __attribute__((ext_vector_type(8))) short bf16x8;
typedef __attribute__((ext_vector_type(4))) float f32x4;

#define GAS __attribute__((address_space(1)))
#define LAS __attribute__((address_space(3)))

static __device__ __forceinline__ void gload16(const __hip_bfloat16* g, void* lds) {
    __builtin_amdgcn_global_load_lds((const GAS uint32_t*)g, (LAS uint32_t*)lds, 16, 0, 0);
}

static __device__ __forceinline__ float bf2f(short u) {
    union { unsigned int x; float f; } c;
    c.x = ((unsigned int)(unsigned short)u) << 16;
    return c.f;
}

// ---------------------------------------------------------------------------
// bf16 MFMA GEMM: C[M,256] += A[M,K] @ BT[256,K]^T   (C fp32 via atomicAdd)
// 64x64 tile, BK=64, 4 waves (2x2), split-K over blockIdx.z.
// LDS: A,B tiles 64 rows x 128B, XOR-swizzled (slot ^= row&7) for
// conflict-free ds_read_b128; swizzle applied on the gload source side.
// ---------------------------------------------------------------------------
__global__ __launch_bounds__(256)
void gemm_bf16_mfma(const __hip_bfloat16* __restrict__ A, int lda,
                    const __hip_bfloat16* __restrict__ BT, int ldb,
                    float* __restrict__ C, int ldc,
                    int kchunk, int niter)
{
    __shared__ __align__(128) char smem[16384];
    char* As = smem;            // 8192 B
    char* Bs = smem + 8192;     // 8192 B

    const int tid  = threadIdx.x;
    const int lane = tid & 63;
    const int wid  = tid >> 6;
    const int wr   = wid >> 1, wc = wid & 1;

    const int n0 = blockIdx.x * 64;
    const int m0 = blockIdx.y * 64;
    const long k0 = (long)blockIdx.z * kchunk;

    const int qk = lane >> 4;           // k quarter 0..3
    const int fr = lane & 15;           // fragment row/col
    const int sw = (lane & 7) << 4;     // read-side xor swizzle (== row&7 <<4)

    f32x4 acc[2][2] = {};

    for (int it = 0; it < niter; ++it) {
        const long kb = k0 + (long)it * 64;
        // ---- stage (global -> LDS, 16B direct, pre-swizzled source) ----
        #pragma unroll
        for (int p = 0; p < 2; ++p) {
            const int chunk = p * 4 + wid;            // wave-uniform
            const int blk   = chunk * 64 + lane;      // 16B block 0..511
            const int r     = blk >> 3;               // tile row 0..63
            const int klog  = ((blk & 7) << 4) ^ ((r & 7) << 4); // logical byte
            gload16(A  + (size_t)(m0 + r) * lda + kb + (klog >> 1), As + chunk * 1024);
            gload16(BT + (size_t)(n0 + r) * ldb + kb + (klog >> 1), Bs + chunk * 1024);
        }
        __syncthreads();
        // ---- compute: 2 k-steps of 32, 4 MFMA each ----
        #pragma unroll
        for (int ks = 0; ks < 2; ++ks) {
            const int ko = ks * 64 + qk * 16;
            bf16x8 a0 = *(const bf16x8*)(As + (wr*32 +      fr) * 128 + (ko ^ sw));
            bf16x8 a1 = *(const bf16x8*)(As + (wr*32 + 16 + fr) * 128 + (ko ^ sw));
            bf16x8 b0 = *(const bf16x8*)(Bs + (wc*32 +      fr) * 128 + (ko ^ sw));
            bf16x8 b1 = *(const bf16x8*)(Bs + (wc*32 + 16 + fr) * 128 + (ko ^ sw));
            acc[0][0] = __builtin_amdgcn_mfma_f32_16x16x32_bf16(a0, b0, acc[0][0], 0, 0, 0);
            acc[0][1] = __builtin_amdgcn_mfma_f32_16x16x32_bf16(a0, b1, acc[0][1], 0, 0, 0);
            acc[1][0] = __builtin_amdgcn_mfma_f32_16x16x32_bf16(a1, b0, acc[1][0], 0, 0, 0);
            acc[1][1] = __builtin_amdgcn_mfma_f32_16x16x32_bf16(a1, b1, acc[1][1], 0, 0, 0);
        }
        __syncthreads();
    }

    // epilogue: C/D layout col=lane&15, row=(lane>>4)*4+reg  [m89-verified]
    #pragma unroll
    for (int mi = 0; mi < 2; ++mi)
        #pragma unroll
        for (int ni = 0; ni < 2; ++ni) {
            const int row = m0 + wr * 32 + mi * 16 + qk * 4;
            const int col = n0 + wc * 32 + ni * 16 + fr;
            #pragma unroll
            for (int q = 0; q < 4; ++q)
                atomicAdd(&C[(size_t)(row + q) * ldc + col], acc[mi][ni][q]);
        }
}

// ---------------------------------------------------------------------------
// fp32 tile GEMM (unchanged from R1) for the phase-B GEMMs
// ---------------------------------------------------------------------------
template<int BM, int BN, int BK, int TM, int TN, int EPI>
__global__ __launch_bounds__(256)
void gemm_f32(const float* __restrict__ A, int lda,
              const float* __restrict__ Bm, int ldb,
              float* __restrict__ C, int ldc,
              int M, int N, int K, int kchunk,
              const float* __restrict__ ep0,
              const float* __restrict__ ep1,
              const float* __restrict__ ep2)
{
    __shared__ float As[BK][BM + 4];
    __shared__ float Bs[BK][BN + 4];

    const int tid = threadIdx.x;
    const int tx = tid % (BN / TN);
    const int ty = tid / (BN / TN);
    const int m0 = blockIdx.y * BM;
    const int n0 = blockIdx.x * BN;

    int kb = 0, ke = K;
    if (kchunk > 0) { kb = blockIdx.z * kchunk; ke = min(K, kb + kchunk); }

    float acc[TM][TN];
    #pragma unroll
    for (int i = 0; i < TM; ++i)
        #pragma unroll
        for (int j = 0; j < TN; ++j) acc[i][j] = 0.f;

    for (int k0 = kb; k0 < ke; k0 += BK) {
        #pragma unroll
        for (int i = tid; i < BM * BK; i += 256) {
            int r = i / BK, c = i % BK;
            int gm = m0 + r, gk = k0 + c;
            As[c][r] = (gm < M && gk < ke) ? A[(size_t)gm * lda + gk] : 0.f;
        }
        #pragma unroll
        for (int i = tid; i < BK * BN; i += 256) {
            int r = i / BN, c = i % BN;
            int gk = k0 + r, gn = n0 + c;
            Bs[r][c] = (gk < ke && gn < N) ? Bm[(size_t)gk * ldb + gn] : 0.f;
        }
        __syncthreads();
        #pragma unroll
        for (int kk = 0; kk < BK; ++kk) {
            float a[TM], b[TN];
            #pragma unroll
            for (int i = 0; i < TM; ++i) a[i] = As[kk][ty * TM + i];
            #pragma unroll
            for (int j = 0; j < TN; ++j) b[j] = Bs[kk][tx * TN + j];
            #pragma unroll
            for (int i = 0; i < TM; ++i)
                #pragma unroll
                for (int j = 0; j < TN; ++j)
                    acc[i][j] += a[i] * b[j];
        }
        __syncthreads();
    }

    #pragma unroll
    for (int i = 0; i < TM; ++i) {
        int row = m0 + ty * TM + i;
        if (row >= M) continue;
        #pragma unroll
        for (int j = 0; j < TN; ++j) {
            int col = n0 + tx * TN + j;
            if (col >= N) continue;
            if (EPI == 0) {
                C[(size_t)row * ldc + col] = acc[i][j];
            } else if (EPI == 1) {
                atomicAdd(&C[(size_t)row * ldc + col], acc[i][j]);
            } else if (EPI == 2) {
                float sv = acc[i][j] + ep0[col];
                C[(size_t)row * ldc + col] = 1.f / (1.f + expf(-sv));
            } else { // EPI == 3
                int nn = row >> 8, bb = row & 255;
                float cg = tanhf(acc[i][j] + ep0[col]);
                float ug = ep1[(size_t)row * 128 + 64 + col];
                float hh = ep2[(size_t)bb * H_ + nn * U_ + col];
                C[(size_t)bb * H_ + nn * U_ + col] = ug * hh + (1.f - ug) * cg;
            }
        }
    }
}

// fp32 -> bf16 convert, 8 elems/thread, grid-stride
__global__ __launch_bounds__(256)
void cvt8_kernel(const float4* __restrict__ in, uint4* __restrict__ out, long n8) {
    long stride = (long)gridDim.x * 256;
    for (long i = blockIdx.x * 256L + threadIdx.x; i < n8; i += stride) {
        float4 x = in[2*i], y = in[2*i+1];
        union { __hip_bfloat16 h[8]; uint4 u; } pk;
        pk.h[0] = __float2bfloat16(x.x); pk.h[1] = __float2bfloat16(x.y);
        pk.h[2] = __float2bfloat16(x.z); pk.h[3] = __float2bfloat16(x.w);
        pk.h[4] = __float2bfloat16(y.x); pk.h[5] = __float2bfloat16(y.y);
        pk.h[6] = __float2bfloat16(y.z); pk.h[7] = __float2bfloat16(y.w);
        out[i] = pk.u;
    }
}

// attn_W (2H, 256) fp32 -> WT_BF (256, 2H) bf16, 32x32 LDS tiles
__global__ __launch_bounds__(256)
void transpose_cvt_kernel(const float* __restrict__ in, __hip_bfloat16* __restrict__ out) {
    __shared__ float tile[32][33];
    const int h0 = blockIdx.x * 32, a0 = blockIdx.y * 32;
    const int tx = threadIdx.x & 31, ty4 = threadIdx.x >> 5;
    #pragma unroll
    for (int i = 0; i < 4; ++i) {
        int r = ty4 * 4 + i;
        tile[r][tx] = in[(size_t)(h0 + r) * A_ + a0 + tx];
    }
    __syncthreads();
    #pragma unroll
    for (int i = 0; i < 4; ++i) {
        int r = ty4 * 4 + i;
        out[(size_t)(a0 + r) * H2_ + h0 + tx] = __float2bfloat16(tile[tx][r]);
    }
}

// T1[b*256+a] = attn_b[a]
__global__ __launch_bounds__(256)
void t1init_kernel(const float* __restrict__ ab, float* __restrict__ T1) {
    int i = blockIdx.x * 256 + threadIdx.x;
    T1[i] = ab[i & 255];
}

// scores[q] = sum_a tanh(P[q,a] + T1[b,a]) * v[a],  q = s*256+b
__global__ __launch_bounds__(256)
void scores_kernel(const float* __restrict__ P, const float* __restrict__ T1,
                   const float* __restrict__ v, float* __restrict__ SC) {
    int wave = threadIdx.x >> 6, lane = threadIdx.x & 63;
    int q = blockIdx.x * 4 + wave;
    if (q >= BS_) return;
    int b = q & 255;
    float s = 0.f;
    #pragma unroll
    for (int a = lane; a < A_; a += 64) {
        float e = tanhf(P[(size_t)q * A_ + a] + T1[b * A_ + a]);
        s += e * v[a];
    }
    #pragma unroll
    for (int off = 32; off; off >>= 1) s += __shfl_down(s, off, 64);
    if (lane == 0) SC[q] = s;
}

__global__ __launch_bounds__(256)
void softmax_kernel(const float* __restrict__ SC, float* __restrict__ AW) {
    int b = threadIdx.x;
    float mx = -1e30f;
    for (int s = 0; s < S_; ++s) mx = fmaxf(mx, SC[s * B_ + b]);
    float sum = 0.f;
    for (int s = 0; s < S_; ++s) sum += expf(SC[s * B_ + b] - mx);
    float inv = 1.f / sum;
    for (int s = 0; s < S_; ++s) AW[s * B_ + b] = expf(SC[s * B_ + b] - mx) * inv;
}

// weighted[b,h] = sum_s AW[s,b] * ENC_BF[s,b,h]  (8 bf16/thread, fp32 out)
__global__ __launch_bounds__(256)
void weighted_bf_kernel(const bf16x8* __restrict__ E, const float* __restrict__ AW,
                        float4* __restrict__ WT4) {
    int g = blockIdx.x * 256 + threadIdx.x;            // B_*H_/8 = 423936
    int b = g / (H_ / 8), c = g % (H_ / 8);
    float f[8] = {0,0,0,0,0,0,0,0};
    #pragma unroll
    for (int s = 0; s < S_; ++s) {
        float w = AW[s * B_ + b];
        bf16x8 ev = E[(size_t)(s * B_ + b) * (H_ / 8) + c];
        #pragma unroll
        for (int j = 0; j < 8; ++j) f[j] += w * bf2f(ev[j]);
    }
    WT4[(size_t)b * (H_ / 4) + 2*c    ] = make_float4(f[0], f[1], f[2], f[3]);
    WT4[(size_t)b * (H_ / 4) + 2*c + 1] = make_float4(f[4], f[5], f[6], f[7]);
}

// CAT (N, B, 129): f=0 -> inputs, 1..64 -> weighted, 65..128 -> hid
__global__ __launch_bounds__(256)
void cat1_kernel(const float* __restrict__ inp, const float* __restrict__ WT,
                 const float* __restrict__ hid, float* __restrict__ CAT) {
    int idx = blockIdx.x * 256 + threadIdx.x;
    if (idx >= N_ * CATW_) return;
    int m = idx / CATW_;
    int rem = idx % CATW_;
    int b = rem / NF_, f = rem % NF_;
    float val;
    if (f == 0)       val = inp[b * N_ + m];
    else if (f <= 64) val = WT[(size_t)b * H_ + m * U_ + (f - 1)];
    else              val = hid[(size_t)b * H_ + m * U_ + (f - 65)];
    CAT[(size_t)idx] = val;
}

__global__ __launch_bounds__(256)
void cat2_kernel(const float* __restrict__ RU, const float* __restrict__ hid,
                 float* __restrict__ CAT) {
    int idx = blockIdx.x * 256 + threadIdx.x;
    if (idx >= N_ * B_ * U_) return;
    int m = idx / (B_ * U_);
    int rem = idx % (B_ * U_);
    int b = rem / U_, u = rem % U_;
    float r = RU[(size_t)(m * B_ + b) * 128 + u];
    float h = hid[(size_t)b * H_ + m * U_ + u];
    CAT[(size_t)m * CATW_ + b * NF_ + 65 + u] = r * h;
}

__global__ __launch_bounds__(256)
void proj_kernel(const float* __restrict__ newh, const float* __restrict__ WT,
                 const float* __restrict__ inp, const float* __restrict__ pW,
                 const float* __restrict__ pb, float* __restrict__ out0) {
    int wave = threadIdx.x >> 6, lane = threadIdx.x & 63;
    int idx = blockIdx.x * 4 + wave;
    if (idx >= B_ * N_) return;
    int b = idx / N_, n = idx % N_;
    float t = newh[(size_t)b * H_ + n * U_ + lane] * pW[lane]
            + WT  [(size_t)b * H_ + n * U_ + lane] * pW[64 + lane];
    if (lane == 0) t += inp[b * N_ + n] * pW[128] + pb[0];
    #pragma unroll
    for (int off = 32; off; off >>= 1) t += __shfl_down(t, off, 64);
    if (lane == 0) out0[b * N_ + n] = t;
}

extern "C" void kernel_launch(void* const* d_in, const int* in_sizes, int n_in,
                              void* d_out, int out_size, void* d_ws, size_t ws_size,
                              hipStream_t stream) {
    const float* inp    = (const float*)d_in[0];
    const float* enc    = (const float*)d_in[1];
    const float* hid    = (const float*)d_in[2];
    const float* adj    = (const float*)d_in[3];
    const float* attn_W = (const float*)d_in[4];
    const float* attn_b = (const float*)d_in[5];
    const float* attn_v = (const float*)d_in[6];
    const float* W_ru   = (const float*)d_in[7];
    const float* b_ru   = (const float*)d_in[8];
    const float* W_c    = (const float*)d_in[9];
    const float* b_c    = (const float*)d_in[10];
    const float* proj_W = (const float*)d_in[11];
    const float* proj_b = (const float*)d_in[12];

    float* out0 = (float*)d_out;
    float* out2 = out0 + (size_t)B_ * N_;

    // Workspace layout (float offsets). ENC_BF aliases CAT/MB/RU (dead after
    // weighted_bf; CAT first written after). Total 50,827,264 floats ≈ 194 MB.
    float* ws  = (float*)d_ws;
    float* T1  = ws;                      // 65536
    float* P   = T1 + 65536;              // 1572864
    float* SC  = P  + 1572864;            // 6144
    float* AW  = SC + 6144;               // 6144
    float* WT  = AW + 6144;               // 3391488
    float* BIG = WT + 3391488;            // region start (off 5042176)
    float* CAT = BIG;                     // 6835968
    float* MB  = CAT + 6835968;           // 6835968
    float* RU  = MB  + 6835968;           // 6782976
    __hip_bfloat16* ENC_BF = (__hip_bfloat16*)BIG;            // 81,395,712 bf16
    __hip_bfloat16* WT_BF  = (__hip_bfloat16*)(BIG + 40697856); // 256 x 26496
    __hip_bfloat16* HID_BF = (__hip_bfloat16*)(BIG + 44089344); // 256 x 13248

    // converts
    cvt8_kernel<<<4096, 256, 0, stream>>>((const float4*)enc, (uint4*)ENC_BF,
                                          (long)BS_ * H_ / 8);
    cvt8_kernel<<<1656, 256, 0, stream>>>((const float4*)hid, (uint4*)HID_BF,
                                          (long)B_ * H_ / 8);
    transpose_cvt_kernel<<<dim3(H2_/32, A_/32), 256, 0, stream>>>(attn_W, WT_BF);

    hipMemsetAsync(P, 0, (size_t)1572864 * sizeof(float), stream);
    t1init_kernel<<<256, 256, 0, stream>>>(attn_b, T1);

    // K1: T1 += hid @ Wh   (M=256, split-K 23, kchunk 576 = 9 iters)
    gemm_bf16_mfma<<<dim3(4, 4, 23), 256, 0, stream>>>(
        HID_BF, H_, WT_BF, H2_, T1, A_, 576, 9);

    // K2: P += enc @ We    (M=6144, split-K 3, kchunk 4416 = 69 iters)
    gemm_bf16_mfma<<<dim3(4, 96, 3), 256, 0, stream>>>(
        ENC_BF, H_, WT_BF + H_, H2_, P, A_, 4416, 69);

    scores_kernel<<<BS_/4, 256, 0, stream>>>(P, T1, attn_v, SC);
    softmax_kernel<<<1, 256, 0, stream>>>(SC, AW);

    // weighted from bf16 enc (L3-resident)
    weighted_bf_kernel<<<(B_*(H_/8))/256, 256, 0, stream>>>(
        (const bf16x8*)ENC_BF, AW, (float4*)WT);

    // ENC_BF dead from here; CAT/MB/RU may overwrite the region.
    cat1_kernel<<<(N_*CATW_)/256, 256, 0, stream>>>(inp, WT, hid, CAT);

    gemm_f32<64,64,16,4,4,0><<<dim3(CATW_/64, 4, 1), 256, 0, stream>>>(
        adj, N_, CAT, CATW_, MB, CATW_, N_, CATW_, N_, 0, nullptr, nullptr, nullptr);

    gemm_f32<64,64,16,4,4,2><<<dim3(2, BN_ROWS_/64, 1), 256, 0, stream>>>(
        MB, NF_, W_ru, 128, RU, 128, BN_ROWS_, 128, NF_, 0, b_ru, nullptr, nullptr);

    cat2_kernel<<<(N_*B_*U_)/256, 256, 0, stream>>>(RU, hid, CAT);

    gemm_f32<64,64,16,4,4,0><<<dim3(CATW_/64, 4, 1), 256, 0, stream>>>(
        adj, N_, CAT, CATW_, MB, CATW_, N_, CATW_, N_, 0, nullptr, nullptr, nullptr);

    gemm_f32<64,64,16,4,4,3><<<dim3(1, BN_ROWS_/64, 1), 256, 0, stream>>>(
        MB, NF_, W_c, U_, out2, U_, BN_ROWS_, U_, NF_, 0, b_c, RU, hid);

    proj_kernel<<<(B_*N_)/4, 256, 0, stream>>>(out2, WT, inp, proj_W, proj_b, out0);
}

// Round 8
// 368.007 us; speedup vs baseline: 5.0167x; 1.5752x over previous
//
#include <hip/hip_runtime.h>
#include <hip/hip_bf16.h>
#include <math.h>

// Problem constants
#define B_ 256
#define S_ 24
#define N_ 207
#define U_ 64
#define A_ 256
#define H_ (N_*U_)          // 13248
#define H2_ (2*H_)          // 26496
#define BS_ (B_*S_)         // 6144
#define NF_ 129             // 1 + 2U
#define FP_ 192             // padded feature width of MB rows
#define KP_ 256             // padded node count (K of adj GEMMs)

typedef __attribute__((ext_vector_type(8))) short bf16x8;
typedef __attribute__((ext_vector_type(4))) float f32x4;

#define GAS __attribute__((address_space(1)))
#define LAS __attribute__((address_space(3)))

static __device__ __forceinline__ void gload16(const __hip_bfloat16* g, void* lds) {
    __builtin_amdgcn_global_load_lds((const GAS uint32_t*)g, (LAS uint32_t*)lds, 16, 0, 0);
}

static __device__ __forceinline__ float bf2f(short u) {
    union { unsigned int x; float f; } c;
    c.x = ((unsigned int)(unsigned short)u) << 16;
    return c.f;
}

// ---------------------------------------------------------------------------
// bf16 MFMA GEMM, 64x64 tile (R2-validated geometry). C = A[M,K] @ BT[N,K]^T.
// fp32 accum; BK=64; 4 waves (2x2); LDS rows 128B XOR-swizzled ((row&7)<<4)
// via pre-swizzled gload source.
// EPI: 1 = fp32 atomicAdd (ldc)
//      2 = bf16 store row-major (ldc)
//      3 = bf16 remap: col=(b,u) -> C[(row*256+b)*FP_+65+u]
//      4 = fp32 sigmoid(acc + ep0[col]) store (ldc)
//      5 = GRU: n=row>>8; b=row&255; c=tanh(acc+ep0[col]);
//          u=ep1[row*128+64+col]; h=ep2[b*H+n*64+col]; out=u*h+(1-u)*c
// ---------------------------------------------------------------------------
template<int EPI>
__global__ __launch_bounds__(256)
void mfma_gemm(const __hip_bfloat16* __restrict__ A, int lda,
               const __hip_bfloat16* __restrict__ BT, int ldb,
               void* __restrict__ Cv, int ldc,
               int kchunk, int niter,
               const float* __restrict__ ep0,
               const float* __restrict__ ep1,
               const float* __restrict__ ep2)
{
    __shared__ __align__(128) char smem[16384];
    char* As = smem;            // 8192 B
    char* Bs = smem + 8192;     // 8192 B

    const int tid  = threadIdx.x;
    const int lane = tid & 63;
    const int wid  = tid >> 6;
    const int wr   = wid >> 1, wc = wid & 1;

    const int n0 = blockIdx.x * 64;
    const int m0 = blockIdx.y * 64;
    const long k0 = (long)blockIdx.z * kchunk;

    const int qk = lane >> 4;
    const int fr = lane & 15;
    const int sw = (lane & 7) << 4;

    f32x4 acc[2][2] = {};

    for (int it = 0; it < niter; ++it) {
        const long kb = k0 + (long)it * 64;
        #pragma unroll
        for (int p = 0; p < 2; ++p) {
            const int chunk = p * 4 + wid;
            const int blk   = chunk * 64 + lane;
            const int r     = blk >> 3;
            const int klog  = ((blk & 7) << 4) ^ ((r & 7) << 4);
            gload16(A  + (size_t)(m0 + r) * lda + kb + (klog >> 1), As + chunk * 1024);
            gload16(BT + (size_t)(n0 + r) * ldb + kb + (klog >> 1), Bs + chunk * 1024);
        }
        __syncthreads();
        #pragma unroll
        for (int ks = 0; ks < 2; ++ks) {
            const int ko = ks * 64 + qk * 16;
            bf16x8 a0 = *(const bf16x8*)(As + (wr*32 +      fr) * 128 + (ko ^ sw));
            bf16x8 a1 = *(const bf16x8*)(As + (wr*32 + 16 + fr) * 128 + (ko ^ sw));
            bf16x8 b0 = *(const bf16x8*)(Bs + (wc*32 +      fr) * 128 + (ko ^ sw));
            bf16x8 b1 = *(const bf16x8*)(Bs + (wc*32 + 16 + fr) * 128 + (ko ^ sw));
            acc[0][0] = __builtin_amdgcn_mfma_f32_16x16x32_bf16(a0, b0, acc[0][0], 0, 0, 0);
            acc[0][1] = __builtin_amdgcn_mfma_f32_16x16x32_bf16(a0, b1, acc[0][1], 0, 0, 0);
            acc[1][0] = __builtin_amdgcn_mfma_f32_16x16x32_bf16(a1, b0, acc[1][0], 0, 0, 0);
            acc[1][1] = __builtin_amdgcn_mfma_f32_16x16x32_bf16(a1, b1, acc[1][1], 0, 0, 0);
        }
        __syncthreads();
    }

    // C/D layout: col=lane&15, row=(lane>>4)*4+reg  [m89-verified]
    #pragma unroll
    for (int mi = 0; mi < 2; ++mi)
        #pragma unroll
        for (int ni = 0; ni < 2; ++ni) {
            const int rbase = m0 + wr * 32 + mi * 16 + qk * 4;
            const int col   = n0 + wc * 32 + ni * 16 + fr;
            #pragma unroll
            for (int q = 0; q < 4; ++q) {
                const int row = rbase + q;
                const float v = acc[mi][ni][q];
                if (EPI == 1) {
                    atomicAdd(&((float*)Cv)[(size_t)row * ldc + col], v);
                } else if (EPI == 2) {
                    ((__hip_bfloat16*)Cv)[(size_t)row * ldc + col] = __float2bfloat16(v);
                } else if (EPI == 3) {
                    const int bb = col >> 6, uu = col & 63;
                    ((__hip_bfloat16*)Cv)[((size_t)row * 256 + bb) * FP_ + 65 + uu] = __float2bfloat16(v);
                } else if (EPI == 4) {
                    float sv = v + ep0[col];
                    ((float*)Cv)[(size_t)row * ldc + col] = 1.f / (1.f + expf(-sv));
                } else { // EPI == 5
                    const int nn = row >> 8, bb = row & 255;
                    float cg = tanhf(v + ep0[col]);
                    float ug = ep1[(size_t)row * 128 + 64 + col];
                    float hh = ep2[(size_t)bb * H_ + nn * U_ + col];
                    ((float*)Cv)[(size_t)bb * H_ + nn * U_ + col] = ug * hh + (1.f - ug) * cg;
                }
            }
        }
}

// zero-fill (float4 granularity, exact count) — replaces hipMemsetAsync(P)
__global__ __launch_bounds__(256)
void zero4_kernel(float4* __restrict__ p) {
    int i = blockIdx.x * 256 + threadIdx.x;
    p[i] = make_float4(0.f, 0.f, 0.f, 0.f);
}

// fp32 -> bf16 convert, 8 elems/thread, grid-stride
__global__ __launch_bounds__(256)
void cvt8_kernel(const float4* __restrict__ in, uint4* __restrict__ out, long n8) {
    long stride = (long)gridDim.x * 256;
    for (long i = blockIdx.x * 256L + threadIdx.x; i < n8; i += stride) {
        float4 x = in[2*i], y = in[2*i+1];
        union { __hip_bfloat16 h[8]; uint4 u; } pk;
        pk.h[0] = __float2bfloat16(x.x); pk.h[1] = __float2bfloat16(x.y);
        pk.h[2] = __float2bfloat16(x.z); pk.h[3] = __float2bfloat16(x.w);
        pk.h[4] = __float2bfloat16(y.x); pk.h[5] = __float2bfloat16(y.y);
        pk.h[6] = __float2bfloat16(y.z); pk.h[7] = __float2bfloat16(y.w);
        out[i] = pk.u;
    }
}

// attn_W (2H, 256) fp32 -> WT_BF (256, 2H) bf16, 32x32 LDS tiles
__global__ __launch_bounds__(256)
void transpose_cvt_kernel(const float* __restrict__ in, __hip_bfloat16* __restrict__ out) {
    __shared__ float tile[32][33];
    const int h0 = blockIdx.x * 32, a0 = blockIdx.y * 32;
    const int tx = threadIdx.x & 31, ty4 = threadIdx.x >> 5;
    #pragma unroll
    for (int i = 0; i < 4; ++i) {
        int r = ty4 * 4 + i;
        tile[r][tx] = in[(size_t)(h0 + r) * A_ + a0 + tx];
    }
    __syncthreads();
    #pragma unroll
    for (int i = 0; i < 4; ++i) {
        int r = ty4 * 4 + i;
        out[(size_t)(a0 + r) * H2_ + h0 + tx] = __float2bfloat16(tile[tx][r]);
    }
}

// adj (207,207) fp32 -> (256,256) bf16 zero-padded
__global__ __launch_bounds__(256)
void adjcvt_kernel(const float* __restrict__ adj, __hip_bfloat16* __restrict__ out) {
    int idx = blockIdx.x * 256 + threadIdx.x;    // 65536
    int r = idx >> 8, c = idx & 255;
    out[idx] = __float2bfloat16((r < N_ && c < N_) ? adj[r * N_ + c] : 0.f);
}

// W_ru (129,128) -> WRUT (128,192) transposed, zero-padded K
__global__ __launch_bounds__(256)
void wruT_kernel(const float* __restrict__ W, __hip_bfloat16* __restrict__ out) {
    int idx = blockIdx.x * 256 + threadIdx.x;    // 24576
    if (idx >= 128 * FP_) return;
    int j = idx / FP_, f = idx % FP_;
    out[idx] = __float2bfloat16(f < NF_ ? W[f * 128 + j] : 0.f);
}

// W_c (129,64) -> WCT (64,192)
__global__ __launch_bounds__(256)
void wcT_kernel(const float* __restrict__ W, __hip_bfloat16* __restrict__ out) {
    int idx = blockIdx.x * 256 + threadIdx.x;    // 12288
    if (idx >= 64 * FP_) return;
    int j = idx / FP_, f = idx % FP_;
    out[idx] = __float2bfloat16(f < NF_ ? W[f * 64 + j] : 0.f);
}

// T1[b*256+a] = attn_b[a]
__global__ __launch_bounds__(256)
void t1init_kernel(const float* __restrict__ ab, float* __restrict__ T1) {
    int i = blockIdx.x * 256 + threadIdx.x;
    T1[i] = ab[i & 255];
}

// scores[q] = sum_a tanh(P[q,a] + T1[b,a]) * v[a],  q = s*256+b
__global__ __launch_bounds__(256)
void scores_kernel(const float* __restrict__ P, const float* __restrict__ T1,
                   const float* __restrict__ v, float* __restrict__ SC) {
    int wave = threadIdx.x >> 6, lane = threadIdx.x & 63;
    int q = blockIdx.x * 4 + wave;
    if (q >= BS_) return;
    int b = q & 255;
    float s = 0.f;
    #pragma unroll
    for (int a = lane; a < A_; a += 64) {
        float e = tanhf(P[(size_t)q * A_ + a] + T1[b * A_ + a]);
        s += e * v[a];
    }
    #pragma unroll
    for (int off = 32; off; off >>= 1) s += __shfl_down(s, off, 64);
    if (lane == 0) SC[q] = s;
}

__global__ __launch_bounds__(256)
void softmax_kernel(const float* __restrict__ SC, float* __restrict__ AW) {
    int b = threadIdx.x;
    float mx = -1e30f;
    for (int s = 0; s < S_; ++s) mx = fmaxf(mx, SC[s * B_ + b]);
    float sum = 0.f;
    for (int s = 0; s < S_; ++s) sum += expf(SC[s * B_ + b] - mx);
    float inv = 1.f / sum;
    for (int s = 0; s < S_; ++s) AW[s * B_ + b] = expf(SC[s * B_ + b] - mx) * inv;
}

// weighted[b,h] = sum_s AW[s,b] * ENC_BF[s,b,h]
__global__ __launch_bounds__(256)
void weighted_bf_kernel(const bf16x8* __restrict__ E, const float* __restrict__ AW,
                        float4* __restrict__ WT4) {
    int g = blockIdx.x * 256 + threadIdx.x;            // B_*H_/8
    int b = g / (H_ / 8), c = g % (H_ / 8);
    float f[8] = {0,0,0,0,0,0,0,0};
    #pragma unroll
    for (int s = 0; s < S_; ++s) {
        float w = AW[s * B_ + b];
        bf16x8 ev = E[(size_t)(s * B_ + b) * (H_ / 8) + c];
        #pragma unroll
        for (int j = 0; j < 8; ++j) f[j] += w * bf2f(ev[j]);
    }
    WT4[(size_t)b * (H_ / 4) + 2*c    ] = make_float4(f[0], f[1], f[2], f[3]);
    WT4[(size_t)b * (H_ / 4) + 2*c + 1] = make_float4(f[4], f[5], f[6], f[7]);
}

// CAT_T builder: rows (b*192+f), cols k (nodes, padded 256), bf16.
// f=0: inputs[b,k]; 1..64: WT[b,k*64+f-1]; 65..128: hid[b,k*64+f-65]; else 0.
__global__ __launch_bounds__(256)
void catT_kernel(const float* __restrict__ inp, const float* __restrict__ WT,
                 const float* __restrict__ hid, __hip_bfloat16* __restrict__ CT) {
    __shared__ float ww[64][65];
    __shared__ float wh[64][65];
    __shared__ float wi[64];
    const int b = blockIdx.x;
    const int k0 = blockIdx.y * 64;
    const int tid = threadIdx.x;
    #pragma unroll
    for (int i = 0; i < 16; ++i) {
        int idx = tid + i * 256;
        int kn = idx >> 6, f = idx & 63;
        int k = k0 + kn;
        bool vld = (k < N_);
        ww[kn][f] = vld ? WT [(size_t)b * H_ + k * 64 + f] : 0.f;
        wh[kn][f] = vld ? hid[(size_t)b * H_ + k * 64 + f] : 0.f;
    }
    if (tid < 64) wi[tid] = (k0 + tid < N_) ? inp[b * N_ + k0 + tid] : 0.f;
    __syncthreads();
    #pragma unroll
    for (int i = 0; i < 6; ++i) {       // 192 rows x 8 chunks = 1536
        int cid = tid + i * 256;
        int f = cid >> 3, kk = (cid & 7) * 8;
        union { __hip_bfloat16 h[8]; bf16x8 v; } pk;
        #pragma unroll
        for (int j = 0; j < 8; ++j) {
            float x;
            if (f == 0)        x = wi[kk + j];
            else if (f <= 64)  x = ww[kk + j][f - 1];
            else if (f <= 128) x = wh[kk + j][f - 65];
            else               x = 0.f;
            pk.h[j] = __float2bfloat16(x);
        }
        *(bf16x8*)(CT + ((size_t)b * FP_ + f) * KP_ + k0 + kk) = pk.v;
    }
}

// RH_T builder: rows (b*64+u), cols k: r[k,b,u]*h[b,k,u], bf16
__global__ __launch_bounds__(256)
void rhT_kernel(const float* __restrict__ RU, const float* __restrict__ hid,
                __hip_bfloat16* __restrict__ RT) {
    __shared__ float rh[64][65];
    const int b = blockIdx.x, k0 = blockIdx.y * 64, tid = threadIdx.x;
    #pragma unroll
    for (int i = 0; i < 16; ++i) {
        int idx = tid + i * 256;
        int kn = idx >> 6, u = idx & 63;
        int k = k0 + kn;
        float v = 0.f;
        if (k < N_)
            v = RU[((size_t)k * 256 + b) * 128 + u] * hid[(size_t)b * H_ + k * 64 + u];
        rh[kn][u] = v;
    }
    __syncthreads();
    #pragma unroll
    for (int i = 0; i < 2; ++i) {       // 64 rows x 8 chunks = 512
        int cid = tid + i * 256;
        int u = cid >> 3, kk = (cid & 7) * 8;
        union { __hip_bfloat16 h[8]; bf16x8 v; } pk;
        #pragma unroll
        for (int j = 0; j < 8; ++j) pk.h[j] = __float2bfloat16(rh[kk + j][u]);
        *(bf16x8*)(RT + ((size_t)b * 64 + u) * KP_ + k0 + kk) = pk.v;
    }
}

__global__ __launch_bounds__(256)
void proj_kernel(const float* __restrict__ newh, const float* __restrict__ WT,
                 const float* __restrict__ inp, const float* __restrict__ pW,
                 const float* __restrict__ pb, float* __restrict__ out0) {
    int wave = threadIdx.x >> 6, lane = threadIdx.x & 63;
    int idx = blockIdx.x * 4 + wave;
    if (idx >= B_ * N_) return;
    int b = idx / N_, n = idx % N_;
    float t = newh[(size_t)b * H_ + n * U_ + lane] * pW[lane]
            + WT  [(size_t)b * H_ + n * U_ + lane] * pW[64 + lane];
    if (lane == 0) t += inp[b * N_ + n] * pW[128] + pb[0];
    #pragma unroll
    for (int off = 32; off; off >>= 1) t += __shfl_down(t, off, 64);
    if (lane == 0) out0[b * N_ + n] = t;
}

extern "C" void kernel_launch(void* const* d_in, const int* in_sizes, int n_in,
                              void* d_out, int out_size, void* d_ws, size_t ws_size,
                              hipStream_t stream) {
    const float* inp    = (const float*)d_in[0];
    const float* enc    = (const float*)d_in[1];
    const float* hid    = (const float*)d_in[2];
    const float* adj    = (const float*)d_in[3];
    const float* attn_W = (const float*)d_in[4];
    const float* attn_b = (const float*)d_in[5];
    const float* attn_v = (const float*)d_in[6];
    const float* W_ru   = (const float*)d_in[7];
    const float* b_ru   = (const float*)d_in[8];
    const float* W_c    = (const float*)d_in[9];
    const float* b_c    = (const float*)d_in[10];
    const float* proj_W = (const float*)d_in[11];
    const float* proj_b = (const float*)d_in[12];

    float* out0 = (float*)d_out;
    float* out2 = out0 + (size_t)B_ * N_;

    // Workspace (float offsets) — EXACT R2-proven footprint: 50,827,264 floats.
    // ENC_BF spans [BIG, BIG+40697856) floats — WT_BF/HID_BF must come AFTER
    // (R3-R7 bug: they were placed inside ENC's span and corrupted it).
    float* ws  = (float*)d_ws;
    float* T1  = ws;                      // 65536
    float* P   = T1 + 65536;              // 1572864
    float* SC  = P  + 1572864;            // 6144
    float* AW  = SC + 6144;               // 6144
    float* WT  = AW + 6144;               // 3391488
    float* BIG = WT + 3391488;            // off 5042176
    __hip_bfloat16* ENC_BF = (__hip_bfloat16*)BIG;               // 81,395,712 bf16 = [0,40697856) fl
    __hip_bfloat16* WT_BF  = (__hip_bfloat16*)(BIG + 40697856);  // 6,782,976 bf16 = [.., 44089344)
    __hip_bfloat16* HID_BF = (__hip_bfloat16*)(BIG + 44089344);  // 3,391,488 bf16 = [.., 50827264 total)
    // Phase-B overlays (first written after weighted_bf, when ENC_BF is dead):
    __hip_bfloat16* CAT_T  = (__hip_bfloat16*)BIG;               // [0, 6291456) fl
    __hip_bfloat16* MB_BF  = (__hip_bfloat16*)(BIG + 6291456);   // [.., 12582912)
    __hip_bfloat16* RH_T   = (__hip_bfloat16*)(BIG + 12582912);  // [.., 14680064)
    float*          RU     = BIG + 14680064;                     // [.., 21463040)
    __hip_bfloat16* ADJ_BF = (__hip_bfloat16*)(BIG + 21463040);  // [.., 21495808)
    __hip_bfloat16* WRUT   = (__hip_bfloat16*)(BIG + 21495808);  // [.., 21508096)
    __hip_bfloat16* WCT    = (__hip_bfloat16*)(BIG + 21508096);  // [.., 21514240) < 40697856 OK

    // --- attention-phase converts ---
    cvt8_kernel<<<4096, 256, 0, stream>>>((const float4*)enc, (uint4*)ENC_BF,
                                          (long)BS_ * H_ / 8);
    cvt8_kernel<<<1656, 256, 0, stream>>>((const float4*)hid, (uint4*)HID_BF,
                                          (long)B_ * H_ / 8);
    transpose_cvt_kernel<<<dim3(H2_/32, A_/32), 256, 0, stream>>>(attn_W, WT_BF);
    t1init_kernel<<<256, 256, 0, stream>>>(attn_b, T1);
    zero4_kernel<<<1536, 256, 0, stream>>>((float4*)P);   // 393216 f4 = whole P

    // --- attention ---
    // K1: T1 += hid @ Wh  (M=256,N=256,K=13248; z=23, 9 iters)
    mfma_gemm<1><<<dim3(4,4,23), 256, 0, stream>>>(
        HID_BF, H_, WT_BF, H2_, T1, A_, 576, 9, nullptr, nullptr, nullptr);
    // K2: P += enc @ We  (M=6144,N=256,K=13248; z=3, 69 iters)
    mfma_gemm<1><<<dim3(4,96,3), 256, 0, stream>>>(
        ENC_BF, H_, WT_BF + H_, H2_, P, A_, 4416, 69, nullptr, nullptr, nullptr);

    scores_kernel<<<BS_/4, 256, 0, stream>>>(P, T1, attn_v, SC);
    softmax_kernel<<<1, 256, 0, stream>>>(SC, AW);
    weighted_bf_kernel<<<(B_*(H_/8))/256, 256, 0, stream>>>(
        (const bf16x8*)ENC_BF, AW, (float4*)WT);

    // --- ENC_BF dead from here; BIG region reused for phase B ---
    adjcvt_kernel<<<256, 256, 0, stream>>>(adj, ADJ_BF);
    wruT_kernel<<<96, 256, 0, stream>>>(W_ru, WRUT);
    wcT_kernel<<<48, 256, 0, stream>>>(W_c, WCT);

    catT_kernel<<<dim3(256,4), 256, 0, stream>>>(inp, WT, hid, CAT_T);

    // m = adj @ cat  (M=256pad, N=49152, K=256pad) -> MB_BF bf16
    mfma_gemm<2><<<dim3(768,4,1), 256, 0, stream>>>(
        ADJ_BF, KP_, CAT_T, KP_, MB_BF, 49152, 0, 4, nullptr, nullptr, nullptr);

    // ru = sigmoid(m @ W_ru + b_ru)  (M=52992, N=128, K=192) -> RU fp32
    mfma_gemm<4><<<dim3(2,828,1), 256, 0, stream>>>(
        MB_BF, FP_, WRUT, FP_, RU, 128, 0, 3, b_ru, nullptr, nullptr);

    // rh rows for second adj product
    rhT_kernel<<<dim3(256,4), 256, 0, stream>>>(RU, hid, RH_T);

    // mc(rh cols) = adj @ rh  (M=256pad, N=16384, K=256pad) -> MB_BF f=65..128
    mfma_gemm<3><<<dim3(256,4,1), 256, 0, stream>>>(
        ADJ_BF, KP_, RH_T, KP_, MB_BF, 0, 0, 4, nullptr, nullptr, nullptr);

    // c = tanh(mc @ W_c + b_c); new_h = u*h + (1-u)*c -> out2
    mfma_gemm<5><<<dim3(1,828,1), 256, 0, stream>>>(
        MB_BF, FP_, WCT, FP_, out2, 0, 0, 3, b_c, RU, hid);

    // output projection
    proj_kernel<<<(B_*N_)/4, 256, 0, stream>>>(out2, WT, inp, proj_W, proj_b, out0);
}

// Round 9
// 352.725 us; speedup vs baseline: 5.2340x; 1.0433x over previous
//
#include <hip/hip_runtime.h>
#include <hip/hip_bf16.h>
#include <math.h>

// Problem constants
#define B_ 256
#define S_ 24
#define N_ 207
#define U_ 64
#define A_ 256
#define H_ (N_*U_)          // 13248
#define H2_ (2*H_)          // 26496
#define BS_ (B_*S_)         // 6144
#define NF_ 129             // 1 + 2U
#define FP_ 192             // padded feature width of MB rows
#define KP_ 256             // padded node count (K of adj GEMMs)

typedef __attribute__((ext_vector_type(8))) short bf16x8;
typedef __attribute__((ext_vector_type(4))) float f32x4;

#define GAS __attribute__((address_space(1)))
#define LAS __attribute__((address_space(3)))

static __device__ __forceinline__ void gload16(const __hip_bfloat16* g, void* lds) {
    __builtin_amdgcn_global_load_lds((const GAS uint32_t*)g, (LAS uint32_t*)lds, 16, 0, 0);
}

static __device__ __forceinline__ float bf2f(short u) {
    union { unsigned int x; float f; } c;
    c.x = ((unsigned int)(unsigned short)u) << 16;
    return c.f;
}

// ---------------------------------------------------------------------------
// bf16 MFMA GEMM, BMxBN tile (64² R2/R8-validated; 128² enabled for K2 only).
// C = A[M,K] @ BT[N,K]^T, fp32 accum; BK=64; 4 waves (2x2), each BM/2 x BN/2.
// LDS rows 128B XOR-swizzled ((row&7)<<4) via pre-swizzled gload source.
// EPI: 1 = fp32 atomicAdd (ldc)
//      2 = bf16 store row-major (ldc)
//      3 = bf16 remap: col=(b,u) -> C[(row*256+b)*FP_+65+u]
//      4 = fp32 sigmoid(acc + ep0[col]) store (ldc)
//      5 = GRU: n=row>>8; b=row&255; c=tanh(acc+ep0[col]);
//          u=ep1[row*128+64+col]; h=ep2[b*H+n*64+col]; out=u*h+(1-u)*c
// ---------------------------------------------------------------------------
template<int BM, int BN, int EPI>
__global__ __launch_bounds__(256)
void mfma_gemm(const __hip_bfloat16* __restrict__ A, int lda,
               const __hip_bfloat16* __restrict__ BT, int ldb,
               void* __restrict__ Cv, int ldc,
               int kchunk, int niter,
               const float* __restrict__ ep0,
               const float* __restrict__ ep1,
               const float* __restrict__ ep2)
{
    constexpr int FM = BM / 32, FN = BN / 32;
    __shared__ __align__(128) char smem[(BM + BN) * 128];
    char* As = smem;
    char* Bs = smem + BM * 128;

    const int tid  = threadIdx.x;
    const int lane = tid & 63;
    const int wid  = tid >> 6;
    const int wr   = wid >> 1, wc = wid & 1;

    const int n0 = blockIdx.x * BN;
    const int m0 = blockIdx.y * BM;
    const long k0 = (long)blockIdx.z * kchunk;

    const int qk = lane >> 4;
    const int fr = lane & 15;
    const int sw = (lane & 7) << 4;

    f32x4 acc[FM][FN] = {};

    for (int it = 0; it < niter; ++it) {
        const long kb = k0 + (long)it * 64;
        #pragma unroll
        for (int p = 0; p < BM / 32; ++p) {
            const int chunk = p * 4 + wid;
            const int blk   = chunk * 64 + lane;
            const int r     = blk >> 3;
            const int klog  = ((blk & 7) << 4) ^ ((r & 7) << 4);
            gload16(A + (size_t)(m0 + r) * lda + kb + (klog >> 1), As + chunk * 1024);
        }
        #pragma unroll
        for (int p = 0; p < BN / 32; ++p) {
            const int chunk = p * 4 + wid;
            const int blk   = chunk * 64 + lane;
            const int r     = blk >> 3;
            const int klog  = ((blk & 7) << 4) ^ ((r & 7) << 4);
            gload16(BT + (size_t)(n0 + r) * ldb + kb + (klog >> 1), Bs + chunk * 1024);
        }
        __syncthreads();
        #pragma unroll
        for (int ks = 0; ks < 2; ++ks) {
            const int ko = ks * 64 + qk * 16;
            bf16x8 a[FM], b[FN];
            #pragma unroll
            for (int i = 0; i < FM; ++i)
                a[i] = *(const bf16x8*)(As + (wr * (BM/2) + i * 16 + fr) * 128 + (ko ^ sw));
            #pragma unroll
            for (int j = 0; j < FN; ++j)
                b[j] = *(const bf16x8*)(Bs + (wc * (BN/2) + j * 16 + fr) * 128 + (ko ^ sw));
            #pragma unroll
            for (int i = 0; i < FM; ++i)
                #pragma unroll
                for (int j = 0; j < FN; ++j)
                    acc[i][j] = __builtin_amdgcn_mfma_f32_16x16x32_bf16(a[i], b[j], acc[i][j], 0, 0, 0);
        }
        __syncthreads();
    }

    // C/D layout: col=lane&15, row=(lane>>4)*4+reg  [m89-verified]
    #pragma unroll
    for (int mi = 0; mi < FM; ++mi)
        #pragma unroll
        for (int ni = 0; ni < FN; ++ni) {
            const int rbase = m0 + wr * (BM/2) + mi * 16 + qk * 4;
            const int col   = n0 + wc * (BN/2) + ni * 16 + fr;
            #pragma unroll
            for (int q = 0; q < 4; ++q) {
                const int row = rbase + q;
                const float v = acc[mi][ni][q];
                if (EPI == 1) {
                    atomicAdd(&((float*)Cv)[(size_t)row * ldc + col], v);
                } else if (EPI == 2) {
                    ((__hip_bfloat16*)Cv)[(size_t)row * ldc + col] = __float2bfloat16(v);
                } else if (EPI == 3) {
                    const int bb = col >> 6, uu = col & 63;
                    ((__hip_bfloat16*)Cv)[((size_t)row * 256 + bb) * FP_ + 65 + uu] = __float2bfloat16(v);
                } else if (EPI == 4) {
                    float sv = v + ep0[col];
                    ((float*)Cv)[(size_t)row * ldc + col] = 1.f / (1.f + expf(-sv));
                } else { // EPI == 5
                    const int nn = row >> 8, bb = row & 255;
                    float cg = tanhf(v + ep0[col]);
                    float ug = ep1[(size_t)row * 128 + 64 + col];
                    float hh = ep2[(size_t)bb * H_ + nn * U_ + col];
                    ((float*)Cv)[(size_t)bb * H_ + nn * U_ + col] = ug * hh + (1.f - ug) * cg;
                }
            }
        }
}

// zero-fill (float4 granularity, exact count) — replaces hipMemsetAsync(P)
__global__ __launch_bounds__(256)
void zero4_kernel(float4* __restrict__ p) {
    int i = blockIdx.x * 256 + threadIdx.x;
    p[i] = make_float4(0.f, 0.f, 0.f, 0.f);
}

// fp32 -> bf16 convert, 8 elems/thread, grid-stride
__global__ __launch_bounds__(256)
void cvt8_kernel(const float4* __restrict__ in, uint4* __restrict__ out, long n8) {
    long stride = (long)gridDim.x * 256;
    for (long i = blockIdx.x * 256L + threadIdx.x; i < n8; i += stride) {
        float4 x = in[2*i], y = in[2*i+1];
        union { __hip_bfloat16 h[8]; uint4 u; } pk;
        pk.h[0] = __float2bfloat16(x.x); pk.h[1] = __float2bfloat16(x.y);
        pk.h[2] = __float2bfloat16(x.z); pk.h[3] = __float2bfloat16(x.w);
        pk.h[4] = __float2bfloat16(y.x); pk.h[5] = __float2bfloat16(y.y);
        pk.h[6] = __float2bfloat16(y.z); pk.h[7] = __float2bfloat16(y.w);
        out[i] = pk.u;
    }
}

// attn_W (2H, 256) fp32 -> WT_BF (256, 2H) bf16, 32x32 LDS tiles
__global__ __launch_bounds__(256)
void transpose_cvt_kernel(const float* __restrict__ in, __hip_bfloat16* __restrict__ out) {
    __shared__ float tile[32][33];
    const int h0 = blockIdx.x * 32, a0 = blockIdx.y * 32;
    const int tx = threadIdx.x & 31, ty4 = threadIdx.x >> 5;
    #pragma unroll
    for (int i = 0; i < 4; ++i) {
        int r = ty4 * 4 + i;
        tile[r][tx] = in[(size_t)(h0 + r) * A_ + a0 + tx];
    }
    __syncthreads();
    #pragma unroll
    for (int i = 0; i < 4; ++i) {
        int r = ty4 * 4 + i;
        out[(size_t)(a0 + r) * H2_ + h0 + tx] = __float2bfloat16(tile[tx][r]);
    }
}

// adj (207,207) fp32 -> (256,256) bf16 zero-padded
__global__ __launch_bounds__(256)
void adjcvt_kernel(const float* __restrict__ adj, __hip_bfloat16* __restrict__ out) {
    int idx = blockIdx.x * 256 + threadIdx.x;    // 65536
    int r = idx >> 8, c = idx & 255;
    out[idx] = __float2bfloat16((r < N_ && c < N_) ? adj[r * N_ + c] : 0.f);
}

// W_ru (129,128) -> WRUT (128,192) transposed, zero-padded K
__global__ __launch_bounds__(256)
void wruT_kernel(const float* __restrict__ W, __hip_bfloat16* __restrict__ out) {
    int idx = blockIdx.x * 256 + threadIdx.x;    // 24576
    if (idx >= 128 * FP_) return;
    int j = idx / FP_, f = idx % FP_;
    out[idx] = __float2bfloat16(f < NF_ ? W[f * 128 + j] : 0.f);
}

// W_c (129,64) -> WCT (64,192)
__global__ __launch_bounds__(256)
void wcT_kernel(const float* __restrict__ W, __hip_bfloat16* __restrict__ out) {
    int idx = blockIdx.x * 256 + threadIdx.x;    // 12288
    if (idx >= 64 * FP_) return;
    int j = idx / FP_, f = idx % FP_;
    out[idx] = __float2bfloat16(f < NF_ ? W[f * 64 + j] : 0.f);
}

// T1[b*256+a] = attn_b[a]
__global__ __launch_bounds__(256)
void t1init_kernel(const float* __restrict__ ab, float* __restrict__ T1) {
    int i = blockIdx.x * 256 + threadIdx.x;
    T1[i] = ab[i & 255];
}

// scores[q] = sum_a tanh(P[q,a] + T1[b,a]) * v[a],  q = s*256+b
__global__ __launch_bounds__(256)
void scores_kernel(const float* __restrict__ P, const float* __restrict__ T1,
                   const float* __restrict__ v, float* __restrict__ SC) {
    int wave = threadIdx.x >> 6, lane = threadIdx.x & 63;
    int q = blockIdx.x * 4 + wave;
    if (q >= BS_) return;
    int b = q & 255;
    float s = 0.f;
    #pragma unroll
    for (int a = lane; a < A_; a += 64) {
        float e = tanhf(P[(size_t)q * A_ + a] + T1[b * A_ + a]);
        s += e * v[a];
    }
    #pragma unroll
    for (int off = 32; off; off >>= 1) s += __shfl_down(s, off, 64);
    if (lane == 0) SC[q] = s;
}

__global__ __launch_bounds__(256)
void softmax_kernel(const float* __restrict__ SC, float* __restrict__ AW) {
    int b = threadIdx.x;
    float mx = -1e30f;
    for (int s = 0; s < S_; ++s) mx = fmaxf(mx, SC[s * B_ + b]);
    float sum = 0.f;
    for (int s = 0; s < S_; ++s) sum += expf(SC[s * B_ + b] - mx);
    float inv = 1.f / sum;
    for (int s = 0; s < S_; ++s) AW[s * B_ + b] = expf(SC[s * B_ + b] - mx) * inv;
}

// weighted[b,h] = sum_s AW[s,b] * ENC_BF[s,b,h]
__global__ __launch_bounds__(256)
void weighted_bf_kernel(const bf16x8* __restrict__ E, const float* __restrict__ AW,
                        float4* __restrict__ WT4) {
    int g = blockIdx.x * 256 + threadIdx.x;            // B_*H_/8
    int b = g / (H_ / 8), c = g % (H_ / 8);
    float f[8] = {0,0,0,0,0,0,0,0};
    #pragma unroll
    for (int s = 0; s < S_; ++s) {
        float w = AW[s * B_ + b];
        bf16x8 ev = E[(size_t)(s * B_ + b) * (H_ / 8) + c];
        #pragma unroll
        for (int j = 0; j < 8; ++j) f[j] += w * bf2f(ev[j]);
    }
    WT4[(size_t)b * (H_ / 4) + 2*c    ] = make_float4(f[0], f[1], f[2], f[3]);
    WT4[(size_t)b * (H_ / 4) + 2*c + 1] = make_float4(f[4], f[5], f[6], f[7]);
}

// CAT_T builder: rows (b*192+f), cols k (nodes, padded 256), bf16.
// f=0: inputs[b,k]; 1..64: WT[b,k*64+f-1]; 65..128: hid[b,k*64+f-65]; else 0.
__global__ __launch_bounds__(256)
void catT_kernel(const float* __restrict__ inp, const float* __restrict__ WT,
                 const float* __restrict__ hid, __hip_bfloat16* __restrict__ CT) {
    __shared__ float ww[64][65];
    __shared__ float wh[64][65];
    __shared__ float wi[64];
    const int b = blockIdx.x;
    const int k0 = blockIdx.y * 64;
    const int tid = threadIdx.x;
    #pragma unroll
    for (int i = 0; i < 16; ++i) {
        int idx = tid + i * 256;
        int kn = idx >> 6, f = idx & 63;
        int k = k0 + kn;
        bool vld = (k < N_);
        ww[kn][f] = vld ? WT [(size_t)b * H_ + k * 64 + f] : 0.f;
        wh[kn][f] = vld ? hid[(size_t)b * H_ + k * 64 + f] : 0.f;
    }
    if (tid < 64) wi[tid] = (k0 + tid < N_) ? inp[b * N_ + k0 + tid] : 0.f;
    __syncthreads();
    #pragma unroll
    for (int i = 0; i < 6; ++i) {       // 192 rows x 8 chunks = 1536
        int cid = tid + i * 256;
        int f = cid >> 3, kk = (cid & 7) * 8;
        union { __hip_bfloat16 h[8]; bf16x8 v; } pk;
        #pragma unroll
        for (int j = 0; j < 8; ++j) {
            float x;
            if (f == 0)        x = wi[kk + j];
            else if (f <= 64)  x = ww[kk + j][f - 1];
            else if (f <= 128) x = wh[kk + j][f - 65];
            else               x = 0.f;
            pk.h[j] = __float2bfloat16(x);
        }
        *(bf16x8*)(CT + ((size_t)b * FP_ + f) * KP_ + k0 + kk) = pk.v;
    }
}

// RH_T builder: rows (b*64+u), cols k: r[k,b,u]*h[b,k,u], bf16
__global__ __launch_bounds__(256)
void rhT_kernel(const float* __restrict__ RU, const float* __restrict__ hid,
                __hip_bfloat16* __restrict__ RT) {
    __shared__ float rh[64][65];
    const int b = blockIdx.x, k0 = blockIdx.y * 64, tid = threadIdx.x;
    #pragma unroll
    for (int i = 0; i < 16; ++i) {
        int idx = tid + i * 256;
        int kn = idx >> 6, u = idx & 63;
        int k = k0 + kn;
        float v = 0.f;
        if (k < N_)
            v = RU[((size_t)k * 256 + b) * 128 + u] * hid[(size_t)b * H_ + k * 64 + u];
        rh[kn][u] = v;
    }
    __syncthreads();
    #pragma unroll
    for (int i = 0; i < 2; ++i) {       // 64 rows x 8 chunks = 512
        int cid = tid + i * 256;
        int u = cid >> 3, kk = (cid & 7) * 8;
        union { __hip_bfloat16 h[8]; bf16x8 v; } pk;
        #pragma unroll
        for (int j = 0; j < 8; ++j) pk.h[j] = __float2bfloat16(rh[kk + j][u]);
        *(bf16x8*)(RT + ((size_t)b * 64 + u) * KP_ + k0 + kk) = pk.v;
    }
}

__global__ __launch_bounds__(256)
void proj_kernel(const float* __restrict__ newh, const float* __restrict__ WT,
                 const float* __restrict__ inp, const float* __restrict__ pW,
                 const float* __restrict__ pb, float* __restrict__ out0) {
    int wave = threadIdx.x >> 6, lane = threadIdx.x & 63;
    int idx = blockIdx.x * 4 + wave;
    if (idx >= B_ * N_) return;
    int b = idx / N_, n = idx % N_;
    float t = newh[(size_t)b * H_ + n * U_ + lane] * pW[lane]
            + WT  [(size_t)b * H_ + n * U_ + lane] * pW[64 + lane];
    if (lane == 0) t += inp[b * N_ + n] * pW[128] + pb[0];
    #pragma unroll
    for (int off = 32; off; off >>= 1) t += __shfl_down(t, off, 64);
    if (lane == 0) out0[b * N_ + n] = t;
}

extern "C" void kernel_launch(void* const* d_in, const int* in_sizes, int n_in,
                              void* d_out, int out_size, void* d_ws, size_t ws_size,
                              hipStream_t stream) {
    const float* inp    = (const float*)d_in[0];
    const float* enc    = (const float*)d_in[1];
    const float* hid    = (const float*)d_in[2];
    const float* adj    = (const float*)d_in[3];
    const float* attn_W = (const float*)d_in[4];
    const float* attn_b = (const float*)d_in[5];
    const float* attn_v = (const float*)d_in[6];
    const float* W_ru   = (const float*)d_in[7];
    const float* b_ru   = (const float*)d_in[8];
    const float* W_c    = (const float*)d_in[9];
    const float* b_c    = (const float*)d_in[10];
    const float* proj_W = (const float*)d_in[11];
    const float* proj_b = (const float*)d_in[12];

    float* out0 = (float*)d_out;
    float* out2 = out0 + (size_t)B_ * N_;

    // Workspace (float offsets) — R8-validated layout: 50,827,264 floats.
    // ENC_BF spans [BIG, BIG+40697856); WT_BF/HID_BF AFTER it (R3-R7 lesson).
    float* ws  = (float*)d_ws;
    float* T1  = ws;                      // 65536
    float* P   = T1 + 65536;              // 1572864
    float* SC  = P  + 1572864;            // 6144
    float* AW  = SC + 6144;               // 6144
    float* WT  = AW + 6144;               // 3391488
    float* BIG = WT + 3391488;            // off 5042176
    __hip_bfloat16* ENC_BF = (__hip_bfloat16*)BIG;               // [0,40697856) fl
    __hip_bfloat16* WT_BF  = (__hip_bfloat16*)(BIG + 40697856);  // [.., 44089344)
    __hip_bfloat16* HID_BF = (__hip_bfloat16*)(BIG + 44089344);  // [.., 50827264)
    // Phase-B overlays (first written after weighted_bf, ENC_BF dead):
    __hip_bfloat16* CAT_T  = (__hip_bfloat16*)BIG;               // [0, 6291456) fl
    __hip_bfloat16* MB_BF  = (__hip_bfloat16*)(BIG + 6291456);   // [.., 12582912)
    __hip_bfloat16* RH_T   = (__hip_bfloat16*)(BIG + 12582912);  // [.., 14680064)
    float*          RU     = BIG + 14680064;                     // [.., 21463040)
    __hip_bfloat16* ADJ_BF = (__hip_bfloat16*)(BIG + 21463040);  // [.., 21495808)
    __hip_bfloat16* WRUT   = (__hip_bfloat16*)(BIG + 21495808);  // [.., 21508096)
    __hip_bfloat16* WCT    = (__hip_bfloat16*)(BIG + 21508096);  // [.., 21514240)

    // --- attention-phase converts ---
    cvt8_kernel<<<4096, 256, 0, stream>>>((const float4*)enc, (uint4*)ENC_BF,
                                          (long)BS_ * H_ / 8);
    cvt8_kernel<<<1656, 256, 0, stream>>>((const float4*)hid, (uint4*)HID_BF,
                                          (long)B_ * H_ / 8);
    transpose_cvt_kernel<<<dim3(H2_/32, A_/32), 256, 0, stream>>>(attn_W, WT_BF);
    t1init_kernel<<<256, 256, 0, stream>>>(attn_b, T1);
    zero4_kernel<<<1536, 256, 0, stream>>>((float4*)P);

    // --- attention ---
    // K1: T1 += hid @ Wh  (M=256,N=256,K=13248; 64² tile, z=23, 9 iters)
    mfma_gemm<64,64,1><<<dim3(4,4,23), 256, 0, stream>>>(
        HID_BF, H_, WT_BF, H2_, T1, A_, 576, 9, nullptr, nullptr, nullptr);
    // K2: P += enc @ We  (M=6144,N=256,K=13248; 128² tile, z=3, 69 iters)
    mfma_gemm<128,128,1><<<dim3(2,48,3), 256, 0, stream>>>(
        ENC_BF, H_, WT_BF + H_, H2_, P, A_, 4416, 69, nullptr, nullptr, nullptr);

    scores_kernel<<<BS_/4, 256, 0, stream>>>(P, T1, attn_v, SC);
    softmax_kernel<<<1, 256, 0, stream>>>(SC, AW);
    weighted_bf_kernel<<<(B_*(H_/8))/256, 256, 0, stream>>>(
        (const bf16x8*)ENC_BF, AW, (float4*)WT);

    // --- ENC_BF dead from here; BIG region reused for phase B ---
    adjcvt_kernel<<<256, 256, 0, stream>>>(adj, ADJ_BF);
    wruT_kernel<<<96, 256, 0, stream>>>(W_ru, WRUT);
    wcT_kernel<<<48, 256, 0, stream>>>(W_c, WCT);

    catT_kernel<<<dim3(256,4), 256, 0, stream>>>(inp, WT, hid, CAT_T);

    // m = adj @ cat  (M=256pad, N=49152, K=256pad) -> MB_BF bf16
    mfma_gemm<64,64,2><<<dim3(768,4,1), 256, 0, stream>>>(
        ADJ_BF, KP_, CAT_T, KP_, MB_BF, 49152, 0, 4, nullptr, nullptr, nullptr);

    // ru = sigmoid(m @ W_ru + b_ru)  (M=52992, N=128, K=192) -> RU fp32
    mfma_gemm<64,64,4><<<dim3(2,828,1), 256, 0, stream>>>(
        MB_BF, FP_, WRUT, FP_, RU, 128, 0, 3, b_ru, nullptr, nullptr);

    // rh rows for second adj product
    rhT_kernel<<<dim3(256,4), 256, 0, stream>>>(RU, hid, RH_T);

    // mc(rh cols) = adj @ rh  (M=256pad, N=16384, K=256pad) -> MB_BF f=65..128
    mfma_gemm<64,64,3><<<dim3(256,4,1), 256, 0, stream>>>(
        ADJ_BF, KP_, RH_T, KP_, MB_BF, 0, 0, 4, nullptr, nullptr, nullptr);

    // c = tanh(mc @ W_c + b_c); new_h = u*h + (1-u)*c -> out2
    mfma_gemm<64,64,5><<<dim3(1,828,1), 256, 0, stream>>>(
        MB_BF, FP_, WCT, FP_, out2, 0, 0, 3, b_c, RU, hid);

    // output projection
    proj_kernel<<<(B_*N_)/4, 256, 0, stream>>>(out2, WT, inp, proj_W, proj_b, out0);
}

// Round 10
// 342.552 us; speedup vs baseline: 5.3895x; 1.0297x over previous
//
#include <hip/hip_runtime.h>
#include <hip/hip_bf16.h>
#include <math.h>

// Problem constants
#define B_ 256
#define S_ 24
#define N_ 207
#define U_ 64
#define A_ 256
#define H_ (N_*U_)          // 13248
#define H2_ (2*H_)          // 26496
#define BS_ (B_*S_)         // 6144
#define NF_ 129             // 1 + 2U
#define FP_ 192             // padded feature width of MB rows
#define KP_ 256             // padded node count (K of adj GEMMs)

typedef __attribute__((ext_vector_type(8))) short bf16x8;
typedef __attribute__((ext_vector_type(4))) float f32x4;

#define GAS __attribute__((address_space(1)))
#define LAS __attribute__((address_space(3)))

static __device__ __forceinline__ void gload16(const __hip_bfloat16* g, void* lds) {
    __builtin_amdgcn_global_load_lds((const GAS uint32_t*)g, (LAS uint32_t*)lds, 16, 0, 0);
}

static __device__ __forceinline__ float bf2f(short u) {
    union { unsigned int x; float f; } c;
    c.x = ((unsigned int)(unsigned short)u) << 16;
    return c.f;
}

// ---------------------------------------------------------------------------
// bf16 MFMA GEMM, BMxBN tile (64² and 128² validated R8/R9; 64x256 for K2).
// C = A[M,K] @ BT[N,K]^T, fp32 accum; BK=64; 4 waves (2x2), each BM/2 x BN/2.
// LDS rows 128B XOR-swizzled ((row&7)<<4) via pre-swizzled gload source.
// EPI: 1 = fp32 atomicAdd (ldc)
//      2 = bf16 store row-major (ldc)
//      3 = bf16 remap: col=(b,u) -> C[(row*256+b)*FP_+65+u]
//      4 = fp32 sigmoid(acc + ep0[col]) store (ldc)
//      5 = GRU: n=row>>8; b=row&255; c=tanh(acc+ep0[col]);
//          u=ep1[row*128+64+col]; h=ep2[b*H+n*64+col]; out=u*h+(1-u)*c
// ---------------------------------------------------------------------------
template<int BM, int BN, int EPI>
__global__ __launch_bounds__(256)
void mfma_gemm(const __hip_bfloat16* __restrict__ A, int lda,
               const __hip_bfloat16* __restrict__ BT, int ldb,
               void* __restrict__ Cv, int ldc,
               int kchunk, int niter,
               const float* __restrict__ ep0,
               const float* __restrict__ ep1,
               const float* __restrict__ ep2)
{
    constexpr int FM = BM / 32, FN = BN / 32;
    __shared__ __align__(128) char smem[(BM + BN) * 128];
    char* As = smem;
    char* Bs = smem + BM * 128;

    const int tid  = threadIdx.x;
    const int lane = tid & 63;
    const int wid  = tid >> 6;
    const int wr   = wid >> 1, wc = wid & 1;

    const int n0 = blockIdx.x * BN;
    const int m0 = blockIdx.y * BM;
    const long k0 = (long)blockIdx.z * kchunk;

    const int qk = lane >> 4;
    const int fr = lane & 15;
    const int sw = (lane & 7) << 4;

    f32x4 acc[FM][FN] = {};

    for (int it = 0; it < niter; ++it) {
        const long kb = k0 + (long)it * 64;
        #pragma unroll
        for (int p = 0; p < BM / 32; ++p) {
            const int chunk = p * 4 + wid;
            const int blk   = chunk * 64 + lane;
            const int r     = blk >> 3;
            const int klog  = ((blk & 7) << 4) ^ ((r & 7) << 4);
            gload16(A + (size_t)(m0 + r) * lda + kb + (klog >> 1), As + chunk * 1024);
        }
        #pragma unroll
        for (int p = 0; p < BN / 32; ++p) {
            const int chunk = p * 4 + wid;
            const int blk   = chunk * 64 + lane;
            const int r     = blk >> 3;
            const int klog  = ((blk & 7) << 4) ^ ((r & 7) << 4);
            gload16(BT + (size_t)(n0 + r) * ldb + kb + (klog >> 1), Bs + chunk * 1024);
        }
        __syncthreads();
        #pragma unroll
        for (int ks = 0; ks < 2; ++ks) {
            const int ko = ks * 64 + qk * 16;
            bf16x8 a[FM], b[FN];
            #pragma unroll
            for (int i = 0; i < FM; ++i)
                a[i] = *(const bf16x8*)(As + (wr * (BM/2) + i * 16 + fr) * 128 + (ko ^ sw));
            #pragma unroll
            for (int j = 0; j < FN; ++j)
                b[j] = *(const bf16x8*)(Bs + (wc * (BN/2) + j * 16 + fr) * 128 + (ko ^ sw));
            #pragma unroll
            for (int i = 0; i < FM; ++i)
                #pragma unroll
                for (int j = 0; j < FN; ++j)
                    acc[i][j] = __builtin_amdgcn_mfma_f32_16x16x32_bf16(a[i], b[j], acc[i][j], 0, 0, 0);
        }
        __syncthreads();
    }

    // C/D layout: col=lane&15, row=(lane>>4)*4+reg  [m89-verified]
    #pragma unroll
    for (int mi = 0; mi < FM; ++mi)
        #pragma unroll
        for (int ni = 0; ni < FN; ++ni) {
            const int rbase = m0 + wr * (BM/2) + mi * 16 + qk * 4;
            const int col   = n0 + wc * (BN/2) + ni * 16 + fr;
            #pragma unroll
            for (int q = 0; q < 4; ++q) {
                const int row = rbase + q;
                const float v = acc[mi][ni][q];
                if (EPI == 1) {
                    atomicAdd(&((float*)Cv)[(size_t)row * ldc + col], v);
                } else if (EPI == 2) {
                    ((__hip_bfloat16*)Cv)[(size_t)row * ldc + col] = __float2bfloat16(v);
                } else if (EPI == 3) {
                    const int bb = col >> 6, uu = col & 63;
                    ((__hip_bfloat16*)Cv)[((size_t)row * 256 + bb) * FP_ + 65 + uu] = __float2bfloat16(v);
                } else if (EPI == 4) {
                    float sv = v + ep0[col];
                    ((float*)Cv)[(size_t)row * ldc + col] = 1.f / (1.f + expf(-sv));
                } else { // EPI == 5
                    const int nn = row >> 8, bb = row & 255;
                    float cg = tanhf(v + ep0[col]);
                    float ug = ep1[(size_t)row * 128 + 64 + col];
                    float hh = ep2[(size_t)bb * H_ + nn * U_ + col];
                    ((float*)Cv)[(size_t)bb * H_ + nn * U_ + col] = ug * hh + (1.f - ug) * cg;
                }
            }
        }
}

// fused init: blocks [0,256): T1[b*256+a] = attn_b[a]; blocks [256,1792): zero P
__global__ __launch_bounds__(256)
void init_kernel(const float* __restrict__ ab, float* __restrict__ T1,
                 float4* __restrict__ P4) {
    int i = blockIdx.x * 256 + threadIdx.x;
    if (blockIdx.x < 256) {
        T1[i] = ab[i & 255];
    } else {
        P4[i - 65536] = make_float4(0.f, 0.f, 0.f, 0.f);
    }
}

// fused phase-B weight prep: adj pad-cvt | W_ru transpose | W_c transpose
// (runs AFTER weighted_bf: outputs overlay ENC_BF's dead span)
__global__ __launch_bounds__(256)
void prepB_kernel(const float* __restrict__ adj, const float* __restrict__ Wru,
                  const float* __restrict__ Wc, __hip_bfloat16* __restrict__ ADJ,
                  __hip_bfloat16* __restrict__ WRUT, __hip_bfloat16* __restrict__ WCT) {
    int i = blockIdx.x * 256 + threadIdx.x;          // 102400 total
    if (i < 65536) {
        int r = i >> 8, c = i & 255;
        ADJ[i] = __float2bfloat16((r < N_ && c < N_) ? adj[r * N_ + c] : 0.f);
    } else if (i < 90112) {
        int idx = i - 65536;                         // 128 x 192
        int j = idx / FP_, f = idx % FP_;
        WRUT[idx] = __float2bfloat16(f < NF_ ? Wru[f * 128 + j] : 0.f);
    } else {
        int idx = i - 90112;                         // 64 x 192
        int j = idx / FP_, f = idx % FP_;
        WCT[idx] = __float2bfloat16(f < NF_ ? Wc[f * 64 + j] : 0.f);
    }
}

// fp32 -> bf16 convert, 8 elems/thread, grid-stride
__global__ __launch_bounds__(256)
void cvt8_kernel(const float4* __restrict__ in, uint4* __restrict__ out, long n8) {
    long stride = (long)gridDim.x * 256;
    for (long i = blockIdx.x * 256L + threadIdx.x; i < n8; i += stride) {
        float4 x = in[2*i], y = in[2*i+1];
        union { __hip_bfloat16 h[8]; uint4 u; } pk;
        pk.h[0] = __float2bfloat16(x.x); pk.h[1] = __float2bfloat16(x.y);
        pk.h[2] = __float2bfloat16(x.z); pk.h[3] = __float2bfloat16(x.w);
        pk.h[4] = __float2bfloat16(y.x); pk.h[5] = __float2bfloat16(y.y);
        pk.h[6] = __float2bfloat16(y.z); pk.h[7] = __float2bfloat16(y.w);
        out[i] = pk.u;
    }
}

// attn_W (2H, 256) fp32 -> WT_BF (256, 2H) bf16, 32x32 LDS tiles
__global__ __launch_bounds__(256)
void transpose_cvt_kernel(const float* __restrict__ in, __hip_bfloat16* __restrict__ out) {
    __shared__ float tile[32][33];
    const int h0 = blockIdx.x * 32, a0 = blockIdx.y * 32;
    const int tx = threadIdx.x & 31, ty4 = threadIdx.x >> 5;
    #pragma unroll
    for (int i = 0; i < 4; ++i) {
        int r = ty4 * 4 + i;
        tile[r][tx] = in[(size_t)(h0 + r) * A_ + a0 + tx];
    }
    __syncthreads();
    #pragma unroll
    for (int i = 0; i < 4; ++i) {
        int r = ty4 * 4 + i;
        out[(size_t)(a0 + r) * H2_ + h0 + tx] = __float2bfloat16(tile[tx][r]);
    }
}

// scores[q] = sum_a tanh(P[q,a] + T1[b,a]) * v[a],  q = s*256+b
__global__ __launch_bounds__(256)
void scores_kernel(const float* __restrict__ P, const float* __restrict__ T1,
                   const float* __restrict__ v, float* __restrict__ SC) {
    int wave = threadIdx.x >> 6, lane = threadIdx.x & 63;
    int q = blockIdx.x * 4 + wave;
    if (q >= BS_) return;
    int b = q & 255;
    float s = 0.f;
    #pragma unroll
    for (int a = lane; a < A_; a += 64) {
        float e = tanhf(P[(size_t)q * A_ + a] + T1[b * A_ + a]);
        s += e * v[a];
    }
    #pragma unroll
    for (int off = 32; off; off >>= 1) s += __shfl_down(s, off, 64);
    if (lane == 0) SC[q] = s;
}

// weighted[b,h] = softmax_s(SC[:,b]) . ENC_BF[:,b,h]  (softmax fused per-thread)
__global__ __launch_bounds__(256)
void weighted_bf_kernel(const bf16x8* __restrict__ E, const float* __restrict__ SC,
                        float4* __restrict__ WT4) {
    int g = blockIdx.x * 256 + threadIdx.x;            // B_*H_/8
    int b = g / (H_ / 8), c = g % (H_ / 8);
    float sc[S_];
    float mx = -1e30f;
    #pragma unroll
    for (int s = 0; s < S_; ++s) { sc[s] = SC[s * B_ + b]; mx = fmaxf(mx, sc[s]); }
    float sum = 0.f;
    #pragma unroll
    for (int s = 0; s < S_; ++s) { sc[s] = expf(sc[s] - mx); sum += sc[s]; }
    float inv = 1.f / sum;
    float f[8] = {0,0,0,0,0,0,0,0};
    #pragma unroll
    for (int s = 0; s < S_; ++s) {
        float w = sc[s] * inv;
        bf16x8 ev = E[(size_t)(s * B_ + b) * (H_ / 8) + c];
        #pragma unroll
        for (int j = 0; j < 8; ++j) f[j] += w * bf2f(ev[j]);
    }
    WT4[(size_t)b * (H_ / 4) + 2*c    ] = make_float4(f[0], f[1], f[2], f[3]);
    WT4[(size_t)b * (H_ / 4) + 2*c + 1] = make_float4(f[4], f[5], f[6], f[7]);
}

// CAT_T builder: rows (b*192+f), cols k (nodes, padded 256), bf16.
// f=0: inputs[b,k]; 1..64: WT[b,k*64+f-1]; 65..128: hid[b,k*64+f-65]; else 0.
__global__ __launch_bounds__(256)
void catT_kernel(const float* __restrict__ inp, const float* __restrict__ WT,
                 const float* __restrict__ hid, __hip_bfloat16* __restrict__ CT) {
    __shared__ float ww[64][65];
    __shared__ float wh[64][65];
    __shared__ float wi[64];
    const int b = blockIdx.x;
    const int k0 = blockIdx.y * 64;
    const int tid = threadIdx.x;
    #pragma unroll
    for (int i = 0; i < 16; ++i) {
        int idx = tid + i * 256;
        int kn = idx >> 6, f = idx & 63;
        int k = k0 + kn;
        bool vld = (k < N_);
        ww[kn][f] = vld ? WT [(size_t)b * H_ + k * 64 + f] : 0.f;
        wh[kn][f] = vld ? hid[(size_t)b * H_ + k * 64 + f] : 0.f;
    }
    if (tid < 64) wi[tid] = (k0 + tid < N_) ? inp[b * N_ + k0 + tid] : 0.f;
    __syncthreads();
    #pragma unroll
    for (int i = 0; i < 6; ++i) {       // 192 rows x 8 chunks = 1536
        int cid = tid + i * 256;
        int f = cid >> 3, kk = (cid & 7) * 8;
        union { __hip_bfloat16 h[8]; bf16x8 v; } pk;
        #pragma unroll
        for (int j = 0; j < 8; ++j) {
            float x;
            if (f == 0)        x = wi[kk + j];
            else if (f <= 64)  x = ww[kk + j][f - 1];
            else if (f <= 128) x = wh[kk + j][f - 65];
            else               x = 0.f;
            pk.h[j] = __float2bfloat16(x);
        }
        *(bf16x8*)(CT + ((size_t)b * FP_ + f) * KP_ + k0 + kk) = pk.v;
    }
}

// RH_T builder: rows (b*64+u), cols k: r[k,b,u]*h[b,k,u], bf16
__global__ __launch_bounds__(256)
void rhT_kernel(const float* __restrict__ RU, const float* __restrict__ hid,
                __hip_bfloat16* __restrict__ RT) {
    __shared__ float rh[64][65];
    const int b = blockIdx.x, k0 = blockIdx.y * 64, tid = threadIdx.x;
    #pragma unroll
    for (int i = 0; i < 16; ++i) {
        int idx = tid + i * 256;
        int kn = idx >> 6, u = idx & 63;
        int k = k0 + kn;
        float v = 0.f;
        if (k < N_)
            v = RU[((size_t)k * 256 + b) * 128 + u] * hid[(size_t)b * H_ + k * 64 + u];
        rh[kn][u] = v;
    }
    __syncthreads();
    #pragma unroll
    for (int i = 0; i < 2; ++i) {       // 64 rows x 8 chunks = 512
        int cid = tid + i * 256;
        int u = cid >> 3, kk = (cid & 7) * 8;
        union { __hip_bfloat16 h[8]; bf16x8 v; } pk;
        #pragma unroll
        for (int j = 0; j < 8; ++j) pk.h[j] = __float2bfloat16(rh[kk + j][u]);
        *(bf16x8*)(RT + ((size_t)b * 64 + u) * KP_ + k0 + kk) = pk.v;
    }
}

__global__ __launch_bounds__(256)
void proj_kernel(const float* __restrict__ newh, const float* __restrict__ WT,
                 const float* __restrict__ inp, const float* __restrict__ pW,
                 const float* __restrict__ pb, float* __restrict__ out0) {
    int wave = threadIdx.x >> 6, lane = threadIdx.x & 63;
    int idx = blockIdx.x * 4 + wave;
    if (idx >= B_ * N_) return;
    int b = idx / N_, n = idx % N_;
    float t = newh[(size_t)b * H_ + n * U_ + lane] * pW[lane]
            + WT  [(size_t)b * H_ + n * U_ + lane] * pW[64 + lane];
    if (lane == 0) t += inp[b * N_ + n] * pW[128] + pb[0];
    #pragma unroll
    for (int off = 32; off; off >>= 1) t += __shfl_down(t, off, 64);
    if (lane == 0) out0[b * N_ + n] = t;
}

extern "C" void kernel_launch(void* const* d_in, const int* in_sizes, int n_in,
                              void* d_out, int out_size, void* d_ws, size_t ws_size,
                              hipStream_t stream) {
    const float* inp    = (const float*)d_in[0];
    const float* enc    = (const float*)d_in[1];
    const float* hid    = (const float*)d_in[2];
    const float* adj    = (const float*)d_in[3];
    const float* attn_W = (const float*)d_in[4];
    const float* attn_b = (const float*)d_in[5];
    const float* attn_v = (const float*)d_in[6];
    const float* W_ru   = (const float*)d_in[7];
    const float* b_ru   = (const float*)d_in[8];
    const float* W_c    = (const float*)d_in[9];
    const float* b_c    = (const float*)d_in[10];
    const float* proj_W = (const float*)d_in[11];
    const float* proj_b = (const float*)d_in[12];

    float* out0 = (float*)d_out;
    float* out2 = out0 + (size_t)B_ * N_;

    // Workspace (float offsets) — R8-validated layout: 50,827,264 floats.
    // ENC_BF spans [BIG, BIG+40697856); WT_BF/HID_BF AFTER it (R3-R7 lesson).
    float* ws  = (float*)d_ws;
    float* T1  = ws;                      // 65536
    float* P   = T1 + 65536;              // 1572864
    float* SC  = P  + 1572864;            // 6144
    float* AW  = SC + 6144;               // 6144 (unused; layout kept stable)
    float* WT  = AW + 6144;               // 3391488
    float* BIG = WT + 3391488;            // off 5042176
    __hip_bfloat16* ENC_BF = (__hip_bfloat16*)BIG;               // [0,40697856) fl
    __hip_bfloat16* WT_BF  = (__hip_bfloat16*)(BIG + 40697856);  // [.., 44089344)
    __hip_bfloat16* HID_BF = (__hip_bfloat16*)(BIG + 44089344);  // [.., 50827264)
    // Phase-B overlays (first written after weighted_bf, ENC_BF dead):
    __hip_bfloat16* CAT_T  = (__hip_bfloat16*)BIG;               // [0, 6291456) fl
    __hip_bfloat16* MB_BF  = (__hip_bfloat16*)(BIG + 6291456);   // [.., 12582912)
    __hip_bfloat16* RH_T   = (__hip_bfloat16*)(BIG + 12582912);  // [.., 14680064)
    float*          RU     = BIG + 14680064;                     // [.., 21463040)
    __hip_bfloat16* ADJ_BF = (__hip_bfloat16*)(BIG + 21463040);  // [.., 21495808)
    __hip_bfloat16* WRUT   = (__hip_bfloat16*)(BIG + 21495808);  // [.., 21508096)
    __hip_bfloat16* WCT    = (__hip_bfloat16*)(BIG + 21508096);  // [.., 21514240)

    // --- attention-phase converts ---
    cvt8_kernel<<<4096, 256, 0, stream>>>((const float4*)enc, (uint4*)ENC_BF,
                                          (long)BS_ * H_ / 8);
    cvt8_kernel<<<1656, 256, 0, stream>>>((const float4*)hid, (uint4*)HID_BF,
                                          (long)B_ * H_ / 8);
    transpose_cvt_kernel<<<dim3(H2_/32, A_/32), 256, 0, stream>>>(attn_W, WT_BF);
    init_kernel<<<1792, 256, 0, stream>>>(attn_b, T1, (float4*)P);

    // --- attention ---
    // K1: T1 += hid @ Wh  (M=256,N=256,K=13248; 64² tile, z=23, 9 iters)
    mfma_gemm<64,64,1><<<dim3(4,4,23), 256, 0, stream>>>(
        HID_BF, H_, WT_BF, H2_, T1, A_, 576, 9, nullptr, nullptr, nullptr);
    // K2: P += enc @ We  (M=6144,N=256,K=13248; 64x256 tile, single n-pass,
    //     z=9, kchunk=1472 = 23 iters exact) — A-panel read exactly once.
    mfma_gemm<64,256,1><<<dim3(1,96,9), 256, 0, stream>>>(
        ENC_BF, H_, WT_BF + H_, H2_, P, A_, 1472, 23, nullptr, nullptr, nullptr);

    scores_kernel<<<BS_/4, 256, 0, stream>>>(P, T1, attn_v, SC);
    // softmax fused into weighted (per-thread recompute from SC)
    weighted_bf_kernel<<<(B_*(H_/8))/256, 256, 0, stream>>>(
        (const bf16x8*)ENC_BF, SC, (float4*)WT);

    // --- ENC_BF dead from here; BIG region reused for phase B ---
    prepB_kernel<<<400, 256, 0, stream>>>(adj, W_ru, W_c, ADJ_BF, WRUT, WCT);

    catT_kernel<<<dim3(256,4), 256, 0, stream>>>(inp, WT, hid, CAT_T);

    // m = adj @ cat  (M=256pad, N=49152, K=256pad) -> MB_BF bf16
    mfma_gemm<64,64,2><<<dim3(768,4,1), 256, 0, stream>>>(
        ADJ_BF, KP_, CAT_T, KP_, MB_BF, 49152, 0, 4, nullptr, nullptr, nullptr);

    // ru = sigmoid(m @ W_ru + b_ru)  (M=52992, N=128, K=192) -> RU fp32
    mfma_gemm<64,64,4><<<dim3(2,828,1), 256, 0, stream>>>(
        MB_BF, FP_, WRUT, FP_, RU, 128, 0, 3, b_ru, nullptr, nullptr);

    // rh rows for second adj product
    rhT_kernel<<<dim3(256,4), 256, 0, stream>>>(RU, hid, RH_T);

    // mc(rh cols) = adj @ rh  (M=256pad, N=16384, K=256pad) -> MB_BF f=65..128
    mfma_gemm<64,64,3><<<dim3(256,4,1), 256, 0, stream>>>(
        ADJ_BF, KP_, RH_T, KP_, MB_BF, 0, 0, 4, nullptr, nullptr, nullptr);

    // c = tanh(mc @ W_c + b_c); new_h = u*h + (1-u)*c -> out2
    mfma_gemm<64,64,5><<<dim3(1,828,1), 256, 0, stream>>>(
        MB_BF, FP_, WCT, FP_, out2, 0, 0, 3, b_c, RU, hid);

    // output projection
    proj_kernel<<<(B_*N_)/4, 256, 0, stream>>>(out2, WT, inp, proj_W, proj_b, out0);
}

// Round 11
// 322.484 us; speedup vs baseline: 5.7249x; 1.0622x over previous
//
#include <hip/hip_runtime.h>
#include <hip/hip_bf16.h>
#include <math.h>

// Problem constants
#define B_ 256
#define S_ 24
#define N_ 207
#define U_ 64
#define A_ 256
#define H_ (N_*U_)          // 13248
#define H2_ (2*H_)          // 26496
#define BS_ (B_*S_)         // 6144
#define NF_ 129             // 1 + 2U
#define FP_ 192             // padded feature width of MB rows
#define KP_ 256             // padded node count (K of adj GEMMs)

typedef __attribute__((ext_vector_type(8))) short bf16x8;
typedef __attribute__((ext_vector_type(4))) float f32x4;

#define GAS __attribute__((address_space(1)))
#define LAS __attribute__((address_space(3)))

static __device__ __forceinline__ void gload16(const __hip_bfloat16* g, void* lds) {
    __builtin_amdgcn_global_load_lds((const GAS uint32_t*)g, (LAS uint32_t*)lds, 16, 0, 0);
}

// ---------------------------------------------------------------------------
// bf16 MFMA GEMM template (R8/R9/R10-validated). C = A[M,K] @ BT[N,K]^T.
// EPI: 1 = fp32 atomicAdd; 2 = bf16 store; 3 = bf16 remap (rh cols);
//      4 = sigmoid store; 5 = GRU epilogue.
// ---------------------------------------------------------------------------
template<int BM, int BN, int EPI>
__global__ __launch_bounds__(256)
void mfma_gemm(const __hip_bfloat16* __restrict__ A, int lda,
               const __hip_bfloat16* __restrict__ BT, int ldb,
               void* __restrict__ Cv, int ldc,
               int kchunk, int niter,
               const float* __restrict__ ep0,
               const float* __restrict__ ep1,
               const float* __restrict__ ep2)
{
    constexpr int FM = BM / 32, FN = BN / 32;
    __shared__ __align__(128) char smem[(BM + BN) * 128];
    char* As = smem;
    char* Bs = smem + BM * 128;

    const int tid  = threadIdx.x;
    const int lane = tid & 63;
    const int wid  = tid >> 6;
    const int wr   = wid >> 1, wc = wid & 1;

    const int n0 = blockIdx.x * BN;
    const int m0 = blockIdx.y * BM;
    const long k0 = (long)blockIdx.z * kchunk;

    const int qk = lane >> 4;
    const int fr = lane & 15;
    const int sw = (lane & 7) << 4;

    f32x4 acc[FM][FN] = {};

    for (int it = 0; it < niter; ++it) {
        const long kb = k0 + (long)it * 64;
        #pragma unroll
        for (int p = 0; p < BM / 32; ++p) {
            const int chunk = p * 4 + wid;
            const int blk   = chunk * 64 + lane;
            const int r     = blk >> 3;
            const int klog  = ((blk & 7) << 4) ^ ((r & 7) << 4);
            gload16(A + (size_t)(m0 + r) * lda + kb + (klog >> 1), As + chunk * 1024);
        }
        #pragma unroll
        for (int p = 0; p < BN / 32; ++p) {
            const int chunk = p * 4 + wid;
            const int blk   = chunk * 64 + lane;
            const int r     = blk >> 3;
            const int klog  = ((blk & 7) << 4) ^ ((r & 7) << 4);
            gload16(BT + (size_t)(n0 + r) * ldb + kb + (klog >> 1), Bs + chunk * 1024);
        }
        __syncthreads();
        #pragma unroll
        for (int ks = 0; ks < 2; ++ks) {
            const int ko = ks * 64 + qk * 16;
            bf16x8 a[FM], b[FN];
            #pragma unroll
            for (int i = 0; i < FM; ++i)
                a[i] = *(const bf16x8*)(As + (wr * (BM/2) + i * 16 + fr) * 128 + (ko ^ sw));
            #pragma unroll
            for (int j = 0; j < FN; ++j)
                b[j] = *(const bf16x8*)(Bs + (wc * (BN/2) + j * 16 + fr) * 128 + (ko ^ sw));
            #pragma unroll
            for (int i = 0; i < FM; ++i)
                #pragma unroll
                for (int j = 0; j < FN; ++j)
                    acc[i][j] = __builtin_amdgcn_mfma_f32_16x16x32_bf16(a[i], b[j], acc[i][j], 0, 0, 0);
        }
        __syncthreads();
    }

    // C/D layout: col=lane&15, row=(lane>>4)*4+reg  [m89-verified]
    #pragma unroll
    for (int mi = 0; mi < FM; ++mi)
        #pragma unroll
        for (int ni = 0; ni < FN; ++ni) {
            const int rbase = m0 + wr * (BM/2) + mi * 16 + qk * 4;
            const int col   = n0 + wc * (BN/2) + ni * 16 + fr;
            #pragma unroll
            for (int q = 0; q < 4; ++q) {
                const int row = rbase + q;
                const float v = acc[mi][ni][q];
                if (EPI == 1) {
                    atomicAdd(&((float*)Cv)[(size_t)row * ldc + col], v);
                } else if (EPI == 2) {
                    ((__hip_bfloat16*)Cv)[(size_t)row * ldc + col] = __float2bfloat16(v);
                } else if (EPI == 3) {
                    const int bb = col >> 6, uu = col & 63;
                    ((__hip_bfloat16*)Cv)[((size_t)row * 256 + bb) * FP_ + 65 + uu] = __float2bfloat16(v);
                } else if (EPI == 4) {
                    float sv = v + ep0[col];
                    ((float*)Cv)[(size_t)row * ldc + col] = 1.f / (1.f + expf(-sv));
                } else { // EPI == 5
                    const int nn = row >> 8, bb = row & 255;
                    float cg = tanhf(v + ep0[col]);
                    float ug = ep1[(size_t)row * 128 + 64 + col];
                    float hh = ep2[(size_t)bb * H_ + nn * U_ + col];
                    ((float*)Cv)[(size_t)bb * H_ + nn * U_ + col] = ug * hh + (1.f - ug) * cg;
                }
            }
        }
}

// ---------------------------------------------------------------------------
// K2 specialized: P += enc_f32 @ We_bf^T. BM=64, BN=256, BK=64.
// A staged from fp32 with in-kernel bf16 convert (reg-staged, swizzled
// ds_write — write-side swizzle == the read-side XOR, rule #21 consistent).
// B keeps the validated global_load_lds pre-swizzled path.
// ---------------------------------------------------------------------------
__global__ __launch_bounds__(256)
void gemm_enc(const float* __restrict__ A,                 // enc fp32, lda=H_
              const __hip_bfloat16* __restrict__ BT,       // We^T bf16, ldb=H2_
              float* __restrict__ C, int ldc,
              int kchunk, int niter)
{
    __shared__ __align__(128) char smem[(64 + 256) * 128];
    char* As = smem;            // 8 KB
    char* Bs = smem + 64*128;   // 32 KB

    const int tid  = threadIdx.x;
    const int lane = tid & 63;
    const int wid  = tid >> 6;
    const int wr   = wid >> 1, wc = wid & 1;

    const int m0 = blockIdx.y * 64;
    const long k0 = (long)blockIdx.z * kchunk;

    const int qk = lane >> 4;
    const int fr = lane & 15;
    const int sw = (lane & 7) << 4;

    f32x4 acc[2][8] = {};

    for (int it = 0; it < niter; ++it) {
        const long kb = k0 + (long)it * 64;
        // ---- A: fp32 -> bf16 reg-staged; 512 16B-chunks, 2/thread ----
        #pragma unroll
        for (int h = 0; h < 2; ++h) {
            const int c  = h * 256 + tid;      // chunk 0..511
            const int r  = c >> 3;             // tile row 0..63
            const int kc = c & 7;              // 8-bf16 slot within row
            const float* src = A + (size_t)(m0 + r) * H_ + kb + kc * 8;
            const float4 x = *(const float4*)(src);
            const float4 y = *(const float4*)(src + 4);
            union { __hip_bfloat16 hh[8]; int4 u; } pk;
            pk.hh[0] = __float2bfloat16(x.x); pk.hh[1] = __float2bfloat16(x.y);
            pk.hh[2] = __float2bfloat16(x.z); pk.hh[3] = __float2bfloat16(x.w);
            pk.hh[4] = __float2bfloat16(y.x); pk.hh[5] = __float2bfloat16(y.y);
            pk.hh[6] = __float2bfloat16(y.z); pk.hh[7] = __float2bfloat16(y.w);
            *(int4*)(As + r * 128 + ((kc << 4) ^ ((r & 7) << 4))) = pk.u;
        }
        // ---- B: gload16 pre-swizzled (unchanged) ----
        #pragma unroll
        for (int p = 0; p < 8; ++p) {
            const int chunk = p * 4 + wid;
            const int blk   = chunk * 64 + lane;
            const int r     = blk >> 3;
            const int klog  = ((blk & 7) << 4) ^ ((r & 7) << 4);
            gload16(BT + (size_t)r * H2_ + kb + (klog >> 1), Bs + chunk * 1024);
        }
        __syncthreads();
        #pragma unroll
        for (int ks = 0; ks < 2; ++ks) {
            const int ko = ks * 64 + qk * 16;
            bf16x8 a[2], b[8];
            #pragma unroll
            for (int i = 0; i < 2; ++i)
                a[i] = *(const bf16x8*)(As + (wr * 32 + i * 16 + fr) * 128 + (ko ^ sw));
            #pragma unroll
            for (int j = 0; j < 8; ++j)
                b[j] = *(const bf16x8*)(Bs + (wc * 128 + j * 16 + fr) * 128 + (ko ^ sw));
            #pragma unroll
            for (int i = 0; i < 2; ++i)
                #pragma unroll
                for (int j = 0; j < 8; ++j)
                    acc[i][j] = __builtin_amdgcn_mfma_f32_16x16x32_bf16(a[i], b[j], acc[i][j], 0, 0, 0);
        }
        __syncthreads();
    }

    #pragma unroll
    for (int mi = 0; mi < 2; ++mi)
        #pragma unroll
        for (int ni = 0; ni < 8; ++ni) {
            const int rbase = m0 + wr * 32 + mi * 16 + qk * 4;
            const int col   = wc * 128 + ni * 16 + fr;
            #pragma unroll
            for (int q = 0; q < 4; ++q)
                atomicAdd(&C[(size_t)(rbase + q) * ldc + col], acc[mi][ni][q]);
        }
}

// fused init: blocks [0,256): T1[b*256+a] = attn_b[a]; blocks [256,1792): zero P
__global__ __launch_bounds__(256)
void init_kernel(const float* __restrict__ ab, float* __restrict__ T1,
                 float4* __restrict__ P4) {
    int i = blockIdx.x * 256 + threadIdx.x;
    if (blockIdx.x < 256) {
        T1[i] = ab[i & 255];
    } else {
        P4[i - 65536] = make_float4(0.f, 0.f, 0.f, 0.f);
    }
}

// fused phase-B weight prep: adj pad-cvt | W_ru transpose | W_c transpose
// (runs AFTER weighted: outputs overlay the attention-dead BIG span)
__global__ __launch_bounds__(256)
void prepB_kernel(const float* __restrict__ adj, const float* __restrict__ Wru,
                  const float* __restrict__ Wc, __hip_bfloat16* __restrict__ ADJ,
                  __hip_bfloat16* __restrict__ WRUT, __hip_bfloat16* __restrict__ WCT) {
    int i = blockIdx.x * 256 + threadIdx.x;          // 102400 total
    if (i < 65536) {
        int r = i >> 8, c = i & 255;
        ADJ[i] = __float2bfloat16((r < N_ && c < N_) ? adj[r * N_ + c] : 0.f);
    } else if (i < 90112) {
        int idx = i - 65536;                         // 128 x 192
        int j = idx / FP_, f = idx % FP_;
        WRUT[idx] = __float2bfloat16(f < NF_ ? Wru[f * 128 + j] : 0.f);
    } else {
        int idx = i - 90112;                         // 64 x 192
        int j = idx / FP_, f = idx % FP_;
        WCT[idx] = __float2bfloat16(f < NF_ ? Wc[f * 64 + j] : 0.f);
    }
}

// fp32 -> bf16 convert, 8 elems/thread, grid-stride (hid only now)
__global__ __launch_bounds__(256)
void cvt8_kernel(const float4* __restrict__ in, uint4* __restrict__ out, long n8) {
    long stride = (long)gridDim.x * 256;
    for (long i = blockIdx.x * 256L + threadIdx.x; i < n8; i += stride) {
        float4 x = in[2*i], y = in[2*i+1];
        union { __hip_bfloat16 h[8]; uint4 u; } pk;
        pk.h[0] = __float2bfloat16(x.x); pk.h[1] = __float2bfloat16(x.y);
        pk.h[2] = __float2bfloat16(x.z); pk.h[3] = __float2bfloat16(x.w);
        pk.h[4] = __float2bfloat16(y.x); pk.h[5] = __float2bfloat16(y.y);
        pk.h[6] = __float2bfloat16(y.z); pk.h[7] = __float2bfloat16(y.w);
        out[i] = pk.u;
    }
}

// attn_W (2H, 256) fp32 -> WT_BF (256, 2H) bf16, 32x32 LDS tiles
__global__ __launch_bounds__(256)
void transpose_cvt_kernel(const float* __restrict__ in, __hip_bfloat16* __restrict__ out) {
    __shared__ float tile[32][33];
    const int h0 = blockIdx.x * 32, a0 = blockIdx.y * 32;
    const int tx = threadIdx.x & 31, ty4 = threadIdx.x >> 5;
    #pragma unroll
    for (int i = 0; i < 4; ++i) {
        int r = ty4 * 4 + i;
        tile[r][tx] = in[(size_t)(h0 + r) * A_ + a0 + tx];
    }
    __syncthreads();
    #pragma unroll
    for (int i = 0; i < 4; ++i) {
        int r = ty4 * 4 + i;
        out[(size_t)(a0 + r) * H2_ + h0 + tx] = __float2bfloat16(tile[tx][r]);
    }
}

// scores[q] = sum_a tanh(P[q,a] + T1[b,a]) * v[a],  q = s*256+b
__global__ __launch_bounds__(256)
void scores_kernel(const float* __restrict__ P, const float* __restrict__ T1,
                   const float* __restrict__ v, float* __restrict__ SC) {
    int wave = threadIdx.x >> 6, lane = threadIdx.x & 63;
    int q = blockIdx.x * 4 + wave;
    if (q >= BS_) return;
    int b = q & 255;
    float s = 0.f;
    #pragma unroll
    for (int a = lane; a < A_; a += 64) {
        float e = tanhf(P[(size_t)q * A_ + a] + T1[b * A_ + a]);
        s += e * v[a];
    }
    #pragma unroll
    for (int off = 32; off; off >>= 1) s += __shfl_down(s, off, 64);
    if (lane == 0) SC[q] = s;
}

// weighted[b,h] = softmax_s(SC[:,b]) . enc_f32[:,b,h]  (softmax fused, R1 fp32 path)
__global__ __launch_bounds__(256)
void weighted_f32_kernel(const float4* __restrict__ E4, const float* __restrict__ SC,
                         float4* __restrict__ WT4) {
    int g = blockIdx.x * 256 + threadIdx.x;            // B_*H_/4 = 847872
    int b = g / (H_ / 4), c = g % (H_ / 4);
    float sc[S_];
    float mx = -1e30f;
    #pragma unroll
    for (int s = 0; s < S_; ++s) { sc[s] = SC[s * B_ + b]; mx = fmaxf(mx, sc[s]); }
    float sum = 0.f;
    #pragma unroll
    for (int s = 0; s < S_; ++s) { sc[s] = expf(sc[s] - mx); sum += sc[s]; }
    float inv = 1.f / sum;
    float4 acc = make_float4(0.f, 0.f, 0.f, 0.f);
    #pragma unroll
    for (int s = 0; s < S_; ++s) {
        float w = sc[s] * inv;
        float4 ev = E4[(size_t)(s * B_ + b) * (H_ / 4) + c];
        acc.x += w * ev.x; acc.y += w * ev.y;
        acc.z += w * ev.z; acc.w += w * ev.w;
    }
    WT4[(size_t)b * (H_ / 4) + c] = acc;
}

// CAT_T builder: rows (b*192+f), cols k (nodes, padded 256), bf16.
__global__ __launch_bounds__(256)
void catT_kernel(const float* __restrict__ inp, const float* __restrict__ WT,
                 const float* __restrict__ hid, __hip_bfloat16* __restrict__ CT) {
    __shared__ float ww[64][65];
    __shared__ float wh[64][65];
    __shared__ float wi[64];
    const int b = blockIdx.x;
    const int k0 = blockIdx.y * 64;
    const int tid = threadIdx.x;
    #pragma unroll
    for (int i = 0; i < 16; ++i) {
        int idx = tid + i * 256;
        int kn = idx >> 6, f = idx & 63;
        int k = k0 + kn;
        bool vld = (k < N_);
        ww[kn][f] = vld ? WT [(size_t)b * H_ + k * 64 + f] : 0.f;
        wh[kn][f] = vld ? hid[(size_t)b * H_ + k * 64 + f] : 0.f;
    }
    if (tid < 64) wi[tid] = (k0 + tid < N_) ? inp[b * N_ + k0 + tid] : 0.f;
    __syncthreads();
    #pragma unroll
    for (int i = 0; i < 6; ++i) {       // 192 rows x 8 chunks = 1536
        int cid = tid + i * 256;
        int f = cid >> 3, kk = (cid & 7) * 8;
        union { __hip_bfloat16 h[8]; bf16x8 v; } pk;
        #pragma unroll
        for (int j = 0; j < 8; ++j) {
            float x;
            if (f == 0)        x = wi[kk + j];
            else if (f <= 64)  x = ww[kk + j][f - 1];
            else if (f <= 128) x = wh[kk + j][f - 65];
            else               x = 0.f;
            pk.h[j] = __float2bfloat16(x);
        }
        *(bf16x8*)(CT + ((size_t)b * FP_ + f) * KP_ + k0 + kk) = pk.v;
    }
}

// RH_T builder: rows (b*64+u), cols k: r[k,b,u]*h[b,k,u], bf16
__global__ __launch_bounds__(256)
void rhT_kernel(const float* __restrict__ RU, const float* __restrict__ hid,
                __hip_bfloat16* __restrict__ RT) {
    __shared__ float rh[64][65];
    const int b = blockIdx.x, k0 = blockIdx.y * 64, tid = threadIdx.x;
    #pragma unroll
    for (int i = 0; i < 16; ++i) {
        int idx = tid + i * 256;
        int kn = idx >> 6, u = idx & 63;
        int k = k0 + kn;
        float v = 0.f;
        if (k < N_)
            v = RU[((size_t)k * 256 + b) * 128 + u] * hid[(size_t)b * H_ + k * 64 + u];
        rh[kn][u] = v;
    }
    __syncthreads();
    #pragma unroll
    for (int i = 0; i < 2; ++i) {       // 64 rows x 8 chunks = 512
        int cid = tid + i * 256;
        int u = cid >> 3, kk = (cid & 7) * 8;
        union { __hip_bfloat16 h[8]; bf16x8 v; } pk;
        #pragma unroll
        for (int j = 0; j < 8; ++j) pk.h[j] = __float2bfloat16(rh[kk + j][u]);
        *(bf16x8*)(RT + ((size_t)b * 64 + u) * KP_ + k0 + kk) = pk.v;
    }
}

__global__ __launch_bounds__(256)
void proj_kernel(const float* __restrict__ newh, const float* __restrict__ WT,
                 const float* __restrict__ inp, const float* __restrict__ pW,
                 const float* __restrict__ pb, float* __restrict__ out0) {
    int wave = threadIdx.x >> 6, lane = threadIdx.x & 63;
    int idx = blockIdx.x * 4 + wave;
    if (idx >= B_ * N_) return;
    int b = idx / N_, n = idx % N_;
    float t = newh[(size_t)b * H_ + n * U_ + lane] * pW[lane]
            + WT  [(size_t)b * H_ + n * U_ + lane] * pW[64 + lane];
    if (lane == 0) t += inp[b * N_ + n] * pW[128] + pb[0];
    #pragma unroll
    for (int off = 32; off; off >>= 1) t += __shfl_down(t, off, 64);
    if (lane == 0) out0[b * N_ + n] = t;
}

extern "C" void kernel_launch(void* const* d_in, const int* in_sizes, int n_in,
                              void* d_out, int out_size, void* d_ws, size_t ws_size,
                              hipStream_t stream) {
    const float* inp    = (const float*)d_in[0];
    const float* enc    = (const float*)d_in[1];
    const float* hid    = (const float*)d_in[2];
    const float* adj    = (const float*)d_in[3];
    const float* attn_W = (const float*)d_in[4];
    const float* attn_b = (const float*)d_in[5];
    const float* attn_v = (const float*)d_in[6];
    const float* W_ru   = (const float*)d_in[7];
    const float* b_ru   = (const float*)d_in[8];
    const float* W_c    = (const float*)d_in[9];
    const float* b_c    = (const float*)d_in[10];
    const float* proj_W = (const float*)d_in[11];
    const float* proj_b = (const float*)d_in[12];

    float* out0 = (float*)d_out;
    float* out2 = out0 + (size_t)B_ * N_;

    // Workspace (float offsets) — R8-validated layout kept verbatim; ENC_BF
    // is no longer written (gemm_enc reads enc fp32 directly) but offsets of
    // WT_BF/HID_BF stay put to avoid reintroducing the R3-R7 aliasing class.
    float* ws  = (float*)d_ws;
    float* T1  = ws;                      // 65536
    float* P   = T1 + 65536;              // 1572864
    float* SC  = P  + 1572864;            // 6144
    float* AW  = SC + 6144;               // 6144 (unused; layout kept stable)
    float* WT  = AW + 6144;               // 3391488
    float* BIG = WT + 3391488;            // off 5042176
    __hip_bfloat16* WT_BF  = (__hip_bfloat16*)(BIG + 40697856);  // [.., 44089344)
    __hip_bfloat16* HID_BF = (__hip_bfloat16*)(BIG + 44089344);  // [.., 50827264)
    // Phase-B overlays (first written after weighted, attention-dead span):
    __hip_bfloat16* CAT_T  = (__hip_bfloat16*)BIG;               // [0, 6291456) fl
    __hip_bfloat16* MB_BF  = (__hip_bfloat16*)(BIG + 6291456);   // [.., 12582912)
    __hip_bfloat16* RH_T   = (__hip_bfloat16*)(BIG + 12582912);  // [.., 14680064)
    float*          RU     = BIG + 14680064;                     // [.., 21463040)
    __hip_bfloat16* ADJ_BF = (__hip_bfloat16*)(BIG + 21463040);  // [.., 21495808)
    __hip_bfloat16* WRUT   = (__hip_bfloat16*)(BIG + 21495808);  // [.., 21508096)
    __hip_bfloat16* WCT    = (__hip_bfloat16*)(BIG + 21508096);  // [.., 21514240)

    // --- attention-phase prep (no more 488MB enc conversion round-trip) ---
    cvt8_kernel<<<1656, 256, 0, stream>>>((const float4*)hid, (uint4*)HID_BF,
                                          (long)B_ * H_ / 8);
    transpose_cvt_kernel<<<dim3(H2_/32, A_/32), 256, 0, stream>>>(attn_W, WT_BF);
    init_kernel<<<1792, 256, 0, stream>>>(attn_b, T1, (float4*)P);

    // --- attention ---
    // K1: T1 += hid @ Wh  (M=256,N=256,K=13248; 64² tile, z=23, 9 iters)
    mfma_gemm<64,64,1><<<dim3(4,4,23), 256, 0, stream>>>(
        HID_BF, H_, WT_BF, H2_, T1, A_, 576, 9, nullptr, nullptr, nullptr);
    // K2: P += enc_f32 @ We  (M=6144; 64x256 tile, z=9, kchunk=1472 = 23 iters;
    //     in-kernel fp32->bf16 A staging — enc read exactly once from HBM)
    gemm_enc<<<dim3(1,96,9), 256, 0, stream>>>(
        enc, WT_BF + H_, P, A_, 1472, 23);

    scores_kernel<<<BS_/4, 256, 0, stream>>>(P, T1, attn_v, SC);
    // weighted from fp32 enc (softmax fused per-thread)
    weighted_f32_kernel<<<(B_*(H_/4))/256, 256, 0, stream>>>(
        (const float4*)enc, SC, (float4*)WT);

    // --- attention dead; BIG region reused for phase B ---
    prepB_kernel<<<400, 256, 0, stream>>>(adj, W_ru, W_c, ADJ_BF, WRUT, WCT);

    catT_kernel<<<dim3(256,4), 256, 0, stream>>>(inp, WT, hid, CAT_T);

    // m = adj @ cat  (M=256pad, N=49152, K=256pad) -> MB_BF bf16
    mfma_gemm<64,64,2><<<dim3(768,4,1), 256, 0, stream>>>(
        ADJ_BF, KP_, CAT_T, KP_, MB_BF, 49152, 0, 4, nullptr, nullptr, nullptr);

    // ru = sigmoid(m @ W_ru + b_ru)  (M=52992, N=128, K=192) -> RU fp32
    mfma_gemm<64,64,4><<<dim3(2,828,1), 256, 0, stream>>>(
        MB_BF, FP_, WRUT, FP_, RU, 128, 0, 3, b_ru, nullptr, nullptr);

    // rh rows for second adj product
    rhT_kernel<<<dim3(256,4), 256, 0, stream>>>(RU, hid, RH_T);

    // mc(rh cols) = adj @ rh  (M=256pad, N=16384, K=256pad) -> MB_BF f=65..128
    mfma_gemm<64,64,3><<<dim3(256,4,1), 256, 0, stream>>>(
        ADJ_BF, KP_, RH_T, KP_, MB_BF, 0, 0, 4, nullptr, nullptr, nullptr);

    // c = tanh(mc @ W_c + b_c); new_h = u*h + (1-u)*c -> out2
    mfma_gemm<64,64,5><<<dim3(1,828,1), 256, 0, stream>>>(
        MB_BF, FP_, WCT, FP_, out2, 0, 0, 3, b_c, RU, hid);

    // output projection
    proj_kernel<<<(B_*N_)/4, 256, 0, stream>>>(out2, WT, inp, proj_W, proj_b, out0);
}

// Round 12
// 307.430 us; speedup vs baseline: 6.0052x; 1.0490x over previous
//
#include <hip/hip_runtime.h>
#include <hip/hip_bf16.h>
#include <math.h>

// Problem constants
#define B_ 256
#define S_ 24
#define N_ 207
#define U_ 64
#define A_ 256
#define H_ (N_*U_)          // 13248
#define H2_ (2*H_)          // 26496
#define BS_ (B_*S_)         // 6144
#define NF_ 129             // 1 + 2U
#define FP_ 192             // padded feature width of MB rows
#define KP_ 256             // padded node count (K of adj GEMMs)

typedef __attribute__((ext_vector_type(8))) short bf16x8;
typedef __attribute__((ext_vector_type(4))) float f32x4;

#define GAS __attribute__((address_space(1)))
#define LAS __attribute__((address_space(3)))

static __device__ __forceinline__ void gload16(const __hip_bfloat16* g, void* lds) {
    __builtin_amdgcn_global_load_lds((const GAS uint32_t*)g, (LAS uint32_t*)lds, 16, 0, 0);
}

// ---------------------------------------------------------------------------
// bf16 MFMA GEMM template (R8-R11-validated). C = A[M,K] @ BT[N,K]^T.
// EPI: 1 = fp32 atomicAdd; 2 = bf16 store; 3 = bf16 remap (rh cols);
//      4 = sigmoid store; 5 = GRU epilogue.
// ---------------------------------------------------------------------------
template<int BM, int BN, int EPI>
__global__ __launch_bounds__(256)
void mfma_gemm(const __hip_bfloat16* __restrict__ A, int lda,
               const __hip_bfloat16* __restrict__ BT, int ldb,
               void* __restrict__ Cv, int ldc,
               int kchunk, int niter,
               const float* __restrict__ ep0,
               const float* __restrict__ ep1,
               const float* __restrict__ ep2)
{
    constexpr int FM = BM / 32, FN = BN / 32;
    __shared__ __align__(128) char smem[(BM + BN) * 128];
    char* As = smem;
    char* Bs = smem + BM * 128;

    const int tid  = threadIdx.x;
    const int lane = tid & 63;
    const int wid  = tid >> 6;
    const int wr   = wid >> 1, wc = wid & 1;

    const int n0 = blockIdx.x * BN;
    const int m0 = blockIdx.y * BM;
    const long k0 = (long)blockIdx.z * kchunk;

    const int qk = lane >> 4;
    const int fr = lane & 15;
    const int sw = (lane & 7) << 4;

    f32x4 acc[FM][FN] = {};

    for (int it = 0; it < niter; ++it) {
        const long kb = k0 + (long)it * 64;
        #pragma unroll
        for (int p = 0; p < BM / 32; ++p) {
            const int chunk = p * 4 + wid;
            const int blk   = chunk * 64 + lane;
            const int r     = blk >> 3;
            const int klog  = ((blk & 7) << 4) ^ ((r & 7) << 4);
            gload16(A + (size_t)(m0 + r) * lda + kb + (klog >> 1), As + chunk * 1024);
        }
        #pragma unroll
        for (int p = 0; p < BN / 32; ++p) {
            const int chunk = p * 4 + wid;
            const int blk   = chunk * 64 + lane;
            const int r     = blk >> 3;
            const int klog  = ((blk & 7) << 4) ^ ((r & 7) << 4);
            gload16(BT + (size_t)(n0 + r) * ldb + kb + (klog >> 1), Bs + chunk * 1024);
        }
        __syncthreads();
        #pragma unroll
        for (int ks = 0; ks < 2; ++ks) {
            const int ko = ks * 64 + qk * 16;
            bf16x8 a[FM], b[FN];
            #pragma unroll
            for (int i = 0; i < FM; ++i)
                a[i] = *(const bf16x8*)(As + (wr * (BM/2) + i * 16 + fr) * 128 + (ko ^ sw));
            #pragma unroll
            for (int j = 0; j < FN; ++j)
                b[j] = *(const bf16x8*)(Bs + (wc * (BN/2) + j * 16 + fr) * 128 + (ko ^ sw));
            #pragma unroll
            for (int i = 0; i < FM; ++i)
                #pragma unroll
                for (int j = 0; j < FN; ++j)
                    acc[i][j] = __builtin_amdgcn_mfma_f32_16x16x32_bf16(a[i], b[j], acc[i][j], 0, 0, 0);
        }
        __syncthreads();
    }

    // C/D layout: col=lane&15, row=(lane>>4)*4+reg  [m89-verified]
    #pragma unroll
    for (int mi = 0; mi < FM; ++mi)
        #pragma unroll
        for (int ni = 0; ni < FN; ++ni) {
            const int rbase = m0 + wr * (BM/2) + mi * 16 + qk * 4;
            const int col   = n0 + wc * (BN/2) + ni * 16 + fr;
            #pragma unroll
            for (int q = 0; q < 4; ++q) {
                const int row = rbase + q;
                const float v = acc[mi][ni][q];
                if (EPI == 1) {
                    atomicAdd(&((float*)Cv)[(size_t)row * ldc + col], v);
                } else if (EPI == 2) {
                    ((__hip_bfloat16*)Cv)[(size_t)row * ldc + col] = __float2bfloat16(v);
                } else if (EPI == 3) {
                    const int bb = col >> 6, uu = col & 63;
                    ((__hip_bfloat16*)Cv)[((size_t)row * 256 + bb) * FP_ + 65 + uu] = __float2bfloat16(v);
                } else if (EPI == 4) {
                    float sv = v + ep0[col];
                    ((float*)Cv)[(size_t)row * ldc + col] = 1.f / (1.f + expf(-sv));
                } else { // EPI == 5
                    const int nn = row >> 8, bb = row & 255;
                    float cg = tanhf(v + ep0[col]);
                    float ug = ep1[(size_t)row * 128 + 64 + col];
                    float hh = ep2[(size_t)bb * H_ + nn * U_ + col];
                    ((float*)Cv)[(size_t)bb * H_ + nn * U_ + col] = ug * hh + (1.f - ug) * cg;
                }
            }
        }
}

// ---------------------------------------------------------------------------
// Fused attention GEMM: one dispatch computes BOTH
//   y in [0,96):   P  += enc_f32[y*64 .. ] @ We^T   (BM=64, BN=256)
//   y in [96,100): T1 += hid_f32[(y-96)*64 ..] @ Wh^T
// A staged fp32->bf16 in-kernel (write-side swizzle == read-side XOR);
// B via validated global_load_lds pre-swizzled path. Split-K over z.
// ---------------------------------------------------------------------------
__global__ __launch_bounds__(256)
void gemm_enchid(const float* __restrict__ Aenc,           // enc fp32, lda=H_
                 const float* __restrict__ Ahid,           // hid fp32, lda=H_
                 const __hip_bfloat16* __restrict__ WTBF,  // attn_W^T bf16, ldb=H2_
                 float* __restrict__ P, float* __restrict__ T1,
                 int kchunk, int niter)
{
    __shared__ __align__(128) char smem[(64 + 256) * 128];
    char* As = smem;            // 8 KB
    char* Bs = smem + 64*128;   // 32 KB

    const int tid  = threadIdx.x;
    const int lane = tid & 63;
    const int wid  = tid >> 6;
    const int wr   = wid >> 1, wc = wid & 1;

    const bool isH = (blockIdx.y >= 96);
    const float* A = isH ? Ahid : Aenc;
    const int m0   = (isH ? (blockIdx.y - 96) : blockIdx.y) * 64;
    const __hip_bfloat16* BT = WTBF + (isH ? 0 : H_);   // Wh^T : We^T
    float* C = isH ? T1 : P;

    const long k0 = (long)blockIdx.z * kchunk;

    const int qk = lane >> 4;
    const int fr = lane & 15;
    const int sw = (lane & 7) << 4;

    f32x4 acc[2][8] = {};

    for (int it = 0; it < niter; ++it) {
        const long kb = k0 + (long)it * 64;
        // ---- A: fp32 -> bf16 reg-staged; 512 16B-chunks, 2/thread ----
        #pragma unroll
        for (int h = 0; h < 2; ++h) {
            const int c  = h * 256 + tid;      // chunk 0..511
            const int r  = c >> 3;             // tile row 0..63
            const int kc = c & 7;              // 8-bf16 slot within row
            const float* src = A + (size_t)(m0 + r) * H_ + kb + kc * 8;
            const float4 x = *(const float4*)(src);
            const float4 y = *(const float4*)(src + 4);
            union { __hip_bfloat16 hh[8]; int4 u; } pk;
            pk.hh[0] = __float2bfloat16(x.x); pk.hh[1] = __float2bfloat16(x.y);
            pk.hh[2] = __float2bfloat16(x.z); pk.hh[3] = __float2bfloat16(x.w);
            pk.hh[4] = __float2bfloat16(y.x); pk.hh[5] = __float2bfloat16(y.y);
            pk.hh[6] = __float2bfloat16(y.z); pk.hh[7] = __float2bfloat16(y.w);
            *(int4*)(As + r * 128 + ((kc << 4) ^ ((r & 7) << 4))) = pk.u;
        }
        // ---- B: gload16 pre-swizzled ----
        #pragma unroll
        for (int p = 0; p < 8; ++p) {
            const int chunk = p * 4 + wid;
            const int blk   = chunk * 64 + lane;
            const int r     = blk >> 3;
            const int klog  = ((blk & 7) << 4) ^ ((r & 7) << 4);
            gload16(BT + (size_t)r * H2_ + kb + (klog >> 1), Bs + chunk * 1024);
        }
        __syncthreads();
        #pragma unroll
        for (int ks = 0; ks < 2; ++ks) {
            const int ko = ks * 64 + qk * 16;
            bf16x8 a[2], b[8];
            #pragma unroll
            for (int i = 0; i < 2; ++i)
                a[i] = *(const bf16x8*)(As + (wr * 32 + i * 16 + fr) * 128 + (ko ^ sw));
            #pragma unroll
            for (int j = 0; j < 8; ++j)
                b[j] = *(const bf16x8*)(Bs + (wc * 128 + j * 16 + fr) * 128 + (ko ^ sw));
            #pragma unroll
            for (int i = 0; i < 2; ++i)
                #pragma unroll
                for (int j = 0; j < 8; ++j)
                    acc[i][j] = __builtin_amdgcn_mfma_f32_16x16x32_bf16(a[i], b[j], acc[i][j], 0, 0, 0);
        }
        __syncthreads();
    }

    #pragma unroll
    for (int mi = 0; mi < 2; ++mi)
        #pragma unroll
        for (int ni = 0; ni < 8; ++ni) {
            const int rbase = m0 + wr * 32 + mi * 16 + qk * 4;
            const int col   = wc * 128 + ni * 16 + fr;
            #pragma unroll
            for (int q = 0; q < 4; ++q)
                atomicAdd(&C[(size_t)(rbase + q) * A_ + col], acc[mi][ni][q]);
        }
}

// fused init: blocks [0,256): T1[b*256+a] = attn_b[a]; blocks [256,1792): zero P
__global__ __launch_bounds__(256)
void init_kernel(const float* __restrict__ ab, float* __restrict__ T1,
                 float4* __restrict__ P4) {
    int i = blockIdx.x * 256 + threadIdx.x;
    if (blockIdx.x < 256) {
        T1[i] = ab[i & 255];
    } else {
        P4[i - 65536] = make_float4(0.f, 0.f, 0.f, 0.f);
    }
}

// attn_W (2H, 256) fp32 -> WT_BF (256, 2H) bf16, 32x32 LDS tiles
__global__ __launch_bounds__(256)
void transpose_cvt_kernel(const float* __restrict__ in, __hip_bfloat16* __restrict__ out) {
    __shared__ float tile[32][33];
    const int h0 = blockIdx.x * 32, a0 = blockIdx.y * 32;
    const int tx = threadIdx.x & 31, ty4 = threadIdx.x >> 5;
    #pragma unroll
    for (int i = 0; i < 4; ++i) {
        int r = ty4 * 4 + i;
        tile[r][tx] = in[(size_t)(h0 + r) * A_ + a0 + tx];
    }
    __syncthreads();
    #pragma unroll
    for (int i = 0; i < 4; ++i) {
        int r = ty4 * 4 + i;
        out[(size_t)(a0 + r) * H2_ + h0 + tx] = __float2bfloat16(tile[tx][r]);
    }
}

// scores[q] = sum_a tanh(P[q,a] + T1[b,a]) * v[a],  q = s*256+b
__global__ __launch_bounds__(256)
void scores_kernel(const float* __restrict__ P, const float* __restrict__ T1,
                   const float* __restrict__ v, float* __restrict__ SC) {
    int wave = threadIdx.x >> 6, lane = threadIdx.x & 63;
    int q = blockIdx.x * 4 + wave;
    if (q >= BS_) return;
    int b = q & 255;
    float s = 0.f;
    #pragma unroll
    for (int a = lane; a < A_; a += 64) {
        float e = tanhf(P[(size_t)q * A_ + a] + T1[b * A_ + a]);
        s += e * v[a];
    }
    #pragma unroll
    for (int off = 32; off; off >>= 1) s += __shfl_down(s, off, 64);
    if (lane == 0) SC[q] = s;
}

// weighted[b,h] = softmax_s(SC[:,b]) . enc_f32[:,b,h]  (softmax fused per-thread)
__global__ __launch_bounds__(256)
void weighted_f32_kernel(const float4* __restrict__ E4, const float* __restrict__ SC,
                         float4* __restrict__ WT4) {
    int g = blockIdx.x * 256 + threadIdx.x;            // B_*H_/4 = 847872
    int b = g / (H_ / 4), c = g % (H_ / 4);
    float sc[S_];
    float mx = -1e30f;
    #pragma unroll
    for (int s = 0; s < S_; ++s) { sc[s] = SC[s * B_ + b]; mx = fmaxf(mx, sc[s]); }
    float sum = 0.f;
    #pragma unroll
    for (int s = 0; s < S_; ++s) { sc[s] = expf(sc[s] - mx); sum += sc[s]; }
    float inv = 1.f / sum;
    float4 acc = make_float4(0.f, 0.f, 0.f, 0.f);
    #pragma unroll
    for (int s = 0; s < S_; ++s) {
        float w = sc[s] * inv;
        float4 ev = E4[(size_t)(s * B_ + b) * (H_ / 4) + c];
        acc.x += w * ev.x; acc.y += w * ev.y;
        acc.z += w * ev.z; acc.w += w * ev.w;
    }
    WT4[(size_t)b * (H_ / 4) + c] = acc;
}

// CAT_T builder (y<4) + phase-B weight prep (y==4, grid-stride).
// CAT_T rows (b*192+f), cols k (nodes, padded 256), bf16.
__global__ __launch_bounds__(256)
void catT_prepB_kernel(const float* __restrict__ inp, const float* __restrict__ WT,
                       const float* __restrict__ hid, __hip_bfloat16* __restrict__ CT,
                       const float* __restrict__ adj, const float* __restrict__ Wru,
                       const float* __restrict__ Wc, __hip_bfloat16* __restrict__ ADJ,
                       __hip_bfloat16* __restrict__ WRUT, __hip_bfloat16* __restrict__ WCT) {
    const int tid = threadIdx.x;
    if (blockIdx.y == 4) {
        // prep slice: 102400 items over 256 blocks, grid-stride
        for (int i = blockIdx.x * 256 + tid; i < 102400; i += 65536) {
            if (i < 65536) {
                int r = i >> 8, c = i & 255;
                ADJ[i] = __float2bfloat16((r < N_ && c < N_) ? adj[r * N_ + c] : 0.f);
            } else if (i < 90112) {
                int idx = i - 65536;                     // 128 x 192
                int j = idx / FP_, f = idx % FP_;
                WRUT[idx] = __float2bfloat16(f < NF_ ? Wru[f * 128 + j] : 0.f);
            } else {
                int idx = i - 90112;                     // 64 x 192
                int j = idx / FP_, f = idx % FP_;
                WCT[idx] = __float2bfloat16(f < NF_ ? Wc[f * 64 + j] : 0.f);
            }
        }
        return;
    }
    __shared__ float ww[64][65];
    __shared__ float wh[64][65];
    __shared__ float wi[64];
    const int b = blockIdx.x;
    const int k0 = blockIdx.y * 64;
    #pragma unroll
    for (int i = 0; i < 16; ++i) {
        int idx = tid + i * 256;
        int kn = idx >> 6, f = idx & 63;
        int k = k0 + kn;
        bool vld = (k < N_);
        ww[kn][f] = vld ? WT [(size_t)b * H_ + k * 64 + f] : 0.f;
        wh[kn][f] = vld ? hid[(size_t)b * H_ + k * 64 + f] : 0.f;
    }
    if (tid < 64) wi[tid] = (k0 + tid < N_) ? inp[b * N_ + k0 + tid] : 0.f;
    __syncthreads();
    #pragma unroll
    for (int i = 0; i < 6; ++i) {       // 192 rows x 8 chunks = 1536
        int cid = tid + i * 256;
        int f = cid >> 3, kk = (cid & 7) * 8;
        union { __hip_bfloat16 h[8]; bf16x8 v; } pk;
        #pragma unroll
        for (int j = 0; j < 8; ++j) {
            float x;
            if (f == 0)        x = wi[kk + j];
            else if (f <= 64)  x = ww[kk + j][f - 1];
            else if (f <= 128) x = wh[kk + j][f - 65];
            else               x = 0.f;
            pk.h[j] = __float2bfloat16(x);
        }
        *(bf16x8*)(CT + ((size_t)b * FP_ + f) * KP_ + k0 + kk) = pk.v;
    }
}

// RH_T builder: rows (b*64+u), cols k: r[k,b,u]*h[b,k,u], bf16
__global__ __launch_bounds__(256)
void rhT_kernel(const float* __restrict__ RU, const float* __restrict__ hid,
                __hip_bfloat16* __restrict__ RT) {
    __shared__ float rh[64][65];
    const int b = blockIdx.x, k0 = blockIdx.y * 64, tid = threadIdx.x;
    #pragma unroll
    for (int i = 0; i < 16; ++i) {
        int idx = tid + i * 256;
        int kn = idx >> 6, u = idx & 63;
        int k = k0 + kn;
        float v = 0.f;
        if (k < N_)
            v = RU[((size_t)k * 256 + b) * 128 + u] * hid[(size_t)b * H_ + k * 64 + u];
        rh[kn][u] = v;
    }
    __syncthreads();
    #pragma unroll
    for (int i = 0; i < 2; ++i) {       // 64 rows x 8 chunks = 512
        int cid = tid + i * 256;
        int u = cid >> 3, kk = (cid & 7) * 8;
        union { __hip_bfloat16 h[8]; bf16x8 v; } pk;
        #pragma unroll
        for (int j = 0; j < 8; ++j) pk.h[j] = __float2bfloat16(rh[kk + j][u]);
        *(bf16x8*)(RT + ((size_t)b * 64 + u) * KP_ + k0 + kk) = pk.v;
    }
}

__global__ __launch_bounds__(256)
void proj_kernel(const float* __restrict__ newh, const float* __restrict__ WT,
                 const float* __restrict__ inp, const float* __restrict__ pW,
                 const float* __restrict__ pb, float* __restrict__ out0) {
    int wave = threadIdx.x >> 6, lane = threadIdx.x & 63;
    int idx = blockIdx.x * 4 + wave;
    if (idx >= B_ * N_) return;
    int b = idx / N_, n = idx % N_;
    float t = newh[(size_t)b * H_ + n * U_ + lane] * pW[lane]
            + WT  [(size_t)b * H_ + n * U_ + lane] * pW[64 + lane];
    if (lane == 0) t += inp[b * N_ + n] * pW[128] + pb[0];
    #pragma unroll
    for (int off = 32; off; off >>= 1) t += __shfl_down(t, off, 64);
    if (lane == 0) out0[b * N_ + n] = t;
}

extern "C" void kernel_launch(void* const* d_in, const int* in_sizes, int n_in,
                              void* d_out, int out_size, void* d_ws, size_t ws_size,
                              hipStream_t stream) {
    const float* inp    = (const float*)d_in[0];
    const float* enc    = (const float*)d_in[1];
    const float* hid    = (const float*)d_in[2];
    const float* adj    = (const float*)d_in[3];
    const float* attn_W = (const float*)d_in[4];
    const float* attn_b = (const float*)d_in[5];
    const float* attn_v = (const float*)d_in[6];
    const float* W_ru   = (const float*)d_in[7];
    const float* b_ru   = (const float*)d_in[8];
    const float* W_c    = (const float*)d_in[9];
    const float* b_c    = (const float*)d_in[10];
    const float* proj_W = (const float*)d_in[11];
    const float* proj_b = (const float*)d_in[12];

    float* out0 = (float*)d_out;
    float* out2 = out0 + (size_t)B_ * N_;

    // Workspace (float offsets) — R8-validated region map kept (HID_BF slot
    // now unused; offsets unchanged to avoid the R3-R7 aliasing class).
    float* ws  = (float*)d_ws;
    float* T1  = ws;                      // 65536
    float* P   = T1 + 65536;              // 1572864
    float* SC  = P  + 1572864;            // 6144
    float* AW  = SC + 6144;               // 6144 (unused; layout kept stable)
    float* WT  = AW + 6144;               // 3391488
    float* BIG = WT + 3391488;            // off 5042176
    __hip_bfloat16* WT_BF  = (__hip_bfloat16*)(BIG + 40697856);  // [.., 44089344)
    // Phase-B overlays (first written after weighted, attention-dead span):
    __hip_bfloat16* CAT_T  = (__hip_bfloat16*)BIG;               // [0, 6291456) fl
    __hip_bfloat16* MB_BF  = (__hip_bfloat16*)(BIG + 6291456);   // [.., 12582912)
    __hip_bfloat16* RH_T   = (__hip_bfloat16*)(BIG + 12582912);  // [.., 14680064)
    float*          RU     = BIG + 14680064;                     // [.., 21463040)
    __hip_bfloat16* ADJ_BF = (__hip_bfloat16*)(BIG + 21463040);  // [.., 21495808)
    __hip_bfloat16* WRUT   = (__hip_bfloat16*)(BIG + 21495808);  // [.., 21508096)
    __hip_bfloat16* WCT    = (__hip_bfloat16*)(BIG + 21508096);  // [.., 21514240)

    // --- attention-phase prep ---
    transpose_cvt_kernel<<<dim3(H2_/32, A_/32), 256, 0, stream>>>(attn_W, WT_BF);
    init_kernel<<<1792, 256, 0, stream>>>(attn_b, T1, (float4*)P);

    // --- attention: ONE dispatch for enc@We (->P) and hid@Wh (->T1) ---
    // y<96: P rows y*64 (M=6144); y in [96,100): T1 rows (y-96)*64 (M=256).
    // z=9 split-K, kchunk=1472 = 23 iters exact; fp32 A staged in-kernel.
    gemm_enchid<<<dim3(1,100,9), 256, 0, stream>>>(
        enc, hid, WT_BF, P, T1, 1472, 23);

    scores_kernel<<<BS_/4, 256, 0, stream>>>(P, T1, attn_v, SC);
    // weighted from fp32 enc (softmax fused per-thread)
    weighted_f32_kernel<<<(B_*(H_/4))/256, 256, 0, stream>>>(
        (const float4*)enc, SC, (float4*)WT);

    // --- attention dead; BIG region reused for phase B ---
    // catT (y<4) + adj/W_ru/W_c prep (y==4) in one dispatch
    catT_prepB_kernel<<<dim3(256,5), 256, 0, stream>>>(
        inp, WT, hid, CAT_T, adj, W_ru, W_c, ADJ_BF, WRUT, WCT);

    // m = adj @ cat  (M=256pad, N=49152, K=256pad) -> MB_BF bf16
    mfma_gemm<64,64,2><<<dim3(768,4,1), 256, 0, stream>>>(
        ADJ_BF, KP_, CAT_T, KP_, MB_BF, 49152, 0, 4, nullptr, nullptr, nullptr);

    // ru = sigmoid(m @ W_ru + b_ru)  (M=52992, N=128, K=192) -> RU fp32
    mfma_gemm<64,64,4><<<dim3(2,828,1), 256, 0, stream>>>(
        MB_BF, FP_, WRUT, FP_, RU, 128, 0, 3, b_ru, nullptr, nullptr);

    // rh rows for second adj product
    rhT_kernel<<<dim3(256,4), 256, 0, stream>>>(RU, hid, RH_T);

    // mc(rh cols) = adj @ rh  (M=256pad, N=16384, K=256pad) -> MB_BF f=65..128
    mfma_gemm<64,64,3><<<dim3(256,4,1), 256, 0, stream>>>(
        ADJ_BF, KP_, RH_T, KP_, MB_BF, 0, 0, 4, nullptr, nullptr, nullptr);

    // c = tanh(mc @ W_c + b_c); new_h = u*h + (1-u)*c -> out2
    mfma_gemm<64,64,5><<<dim3(1,828,1), 256, 0, stream>>>(
        MB_BF, FP_, WCT, FP_, out2, 0, 0, 3, b_c, RU, hid);

    // output projection
    proj_kernel<<<(B_*N_)/4, 256, 0, stream>>>(out2, WT, inp, proj_W, proj_b, out0);
}